// Round 2
// baseline (363.921 us; speedup 1.0000x reference)
//
#include <hip/hip_runtime.h>

#define B_  16
#define S_  128
#define N_  13
#define D_  128
#define E_  6
#define M_  64
#define H_  4

typedef float v2f __attribute__((ext_vector_type(2)));
typedef float v4f __attribute__((ext_vector_type(4)));
typedef short v8s __attribute__((ext_vector_type(8)));

#define MFMA16(A, B, C) __builtin_amdgcn_mfma_f32_16x16x32_bf16((A), (B), (C), 0, 0, 0)
#define LDS_ORDER() __asm__ __volatile__("" ::: "memory")

// ---- workspace layout ----
// floats [0,128): folded biases.  [128, F_TOTAL): u16 node-weight MFMA frag
// tables (hi/lo bf16 split).  Then H region (edge-phase bf16 frag tables).
#define F_BTS   0
#define F_BMC   64
#define F_AOP   128
#define F_TOTAL 61568
// u16 offsets inside the node-frag region (base = (u16*)(ws + F_AOP)):
#define NW_AOH  0
#define NW_AOL  4096
#define NW_AG1H 8192
#define NW_AG1L 16384
#define NW_AG2H 24576
#define NW_AG2L 40960
#define NW_GTH  57344
#define NW_GTL  90112
#define H_EE1   0
#define H_WTS   2048
#define H_TS2   6144
#define H_MC1   8192
#define H_WMCE  16384
#define H_MC2   20480
#define H_ATI   24576
#define H_TOTAL 36864

__device__ __forceinline__ unsigned short f2bs(float x) {  // RTNE fp32->bf16
    unsigned u = __float_as_uint(x);
    u += 0x7FFFu + ((u >> 16) & 1u);
    return (unsigned short)(u >> 16);
}
__device__ __forceinline__ float bs2f(unsigned short h) {
    return __uint_as_float((unsigned)h << 16);
}
__device__ __forceinline__ float erf_fast(float x) {  // A&S 7.1.26, |eps|<1.5e-7
    float ax = fabsf(x);
    float t  = __builtin_amdgcn_rcpf(fmaf(0.3275911f, ax, 1.0f));
    float p  = t * fmaf(t, fmaf(t, fmaf(t, fmaf(t, 1.061405429f, -1.453152027f),
                                        1.421413741f), -0.284496736f), 0.254829592f);
    float r  = fmaf(-p, __expf(-ax * ax), 1.0f);
    return copysignf(r, x);
}
__device__ __forceinline__ float geluf(float x) {
    return 0.5f * x * (1.0f + erf_fast(x * 0.7071067811865475f));
}
__device__ __forceinline__ float sigm(float x) { return 1.0f / (1.0f + __expf(-x)); }
__device__ __forceinline__ v4f gelu4(v4f x) {
    v4f r; r[0] = geluf(x[0]); r[1] = geluf(x[1]); r[2] = geluf(x[2]); r[3] = geluf(x[3]);
    return r;
}

template <bool DOGELU>
__device__ __forceinline__ void ln_c64(v4f &a0, v4f &a1, v4f &a2, v4f &a3,
                                       float g0, float g1, float g2, float g3,
                                       float b0, float b1, float b2, float b3) {
    v4f s = a0 + a1 + a2 + a3;
    v4f q = a0 * a0 + a1 * a1 + a2 * a2 + a3 * a3;
#pragma unroll
    for (int o = 1; o < 16; o <<= 1) {
#pragma unroll
        for (int r = 0; r < 4; r++) {
            s[r] += __shfl_xor(s[r], o, 64);
            q[r] += __shfl_xor(q[r], o, 64);
        }
    }
    v4f mean = s * 0.015625f;
    v4f rs;
#pragma unroll
    for (int r = 0; r < 4; r++) {
        float var = fmaxf(q[r] * 0.015625f - mean[r] * mean[r], 0.f);
        rs[r] = rsqrtf(var + 1e-5f);
    }
    a0 = (a0 - mean) * rs * g0 + b0;
    a1 = (a1 - mean) * rs * g1 + b1;
    a2 = (a2 - mean) * rs * g2 + b2;
    a3 = (a3 - mean) * rs * g3 + b3;
    if (DOGELU) { a0 = gelu4(a0); a1 = gelu4(a1); a2 = gelu4(a2); a3 = gelu4(a3); }
}

template <bool DOGELU>
__device__ __forceinline__ void ln128(float &x0, float &x1, float g0_, float g1_,
                                      float b0_, float b1_) {
    float s = x0 + x1, q = x0 * x0 + x1 * x1;
#pragma unroll
    for (int o = 1; o < 64; o <<= 1) { s += __shfl_xor(s, o, 64); q += __shfl_xor(q, o, 64); }
    float mean = s * (1.f / 128.f);
    float var  = fmaxf(q * (1.f / 128.f) - mean * mean, 0.f);
    float rs   = rsqrtf(var + 1e-5f);
    x0 = (x0 - mean) * rs * g0_ + b0_;
    x1 = (x1 - mean) * rs * g1_ + b1_;
    if (DOGELU) { x0 = geluf(x0); x1 = geluf(x1); }
}

// xp tiles are 15 rows: rows 13/14 are garbage (N_=13); MFMA output row 15
// (g=3,r=3) clamps onto garbage row 14.  Reads of "row 15" clamp likewise.
__device__ __forceinline__ void store_c(unsigned short (*xr)[136], int colbase, int L,
                                        v4f a0, v4f a1, v4f a2, v4f a3) {
    const int c = L & 15, g = L >> 4;
#pragma unroll
    for (int r = 0; r < 4; r++) {
        int rr = 4 * g + r; rr = (rr > 14) ? 14 : rr;
        xr[rr][colbase + c]      = f2bs(a0[r]);
        xr[rr][colbase + 16 + c] = f2bs(a1[r]);
        xr[rr][colbase + 32 + c] = f2bs(a2[r]);
        xr[rr][colbase + 48 + c] = f2bs(a3[r]);
    }
}

__device__ __forceinline__ v8s pack8(v4f lo, v4f hi) {
    v8s r;
    r[0] = (short)f2bs(lo[0]); r[1] = (short)f2bs(lo[1]);
    r[2] = (short)f2bs(lo[2]); r[3] = (short)f2bs(lo[3]);
    r[4] = (short)f2bs(hi[0]); r[5] = (short)f2bs(hi[1]);
    r[6] = (short)f2bs(hi[2]); r[7] = (short)f2bs(hi[3]);
    return r;
}

// write value as bf16 hi + bf16 residual (lo) -- together ~fp32 precision
__device__ __forceinline__ void wr_hl(unsigned short *ph, unsigned short *pl, float v) {
    unsigned short h = f2bs(v);
    *ph = h;
    *pl = f2bs(v - bs2f(h));
}

struct Params {
    const float *node_states, *edge_features;
    const float *ee_w1, *ee_b1, *ee_ln_g, *ee_ln_b, *ee_w2, *ee_b2;
    const float *ts_w1, *ts_b1, *ts_ln_g, *ts_ln_b, *ts_w2, *ts_b2, *ts_w3, *ts_b3;
    const float *mc_w1, *mc_b1, *mc_ln_g, *mc_ln_b, *mc_w2, *mc_b2;
    const float *at_in_w, *at_in_b, *at_out_w, *at_out_b;
    const float *ag_w1, *ag_b1, *ag_ln_g, *ag_ln_b, *ag_w2, *ag_b2;
    const float *gt_w, *gt_b, *nn_ln_g, *nn_ln_b, *mn_ln_g, *mn_ln_b;
    float *ws;
    float *out;
};

__global__ __launch_bounds__(256) void prep_kernel(Params p) {
    int i = blockIdx.x * 256 + threadIdx.x;
    if (i < 128) {   // folded biases
        float v;
        if (i < F_BMC) {
            int o = i - F_BTS;
            float s = p.ts_b1[o];
            for (int e = 0; e < E_; e++) s += p.ee_b2[e] * p.ts_w1[e * M_ + o];
            v = s;
        } else {
            int o = i - F_BMC;
            float s = p.mc_b1[o];
            for (int e = 0; e < E_; e++) s += p.ee_b2[e] * p.mc_w1[(D_ + e) * M_ + o];
            v = s;
        }
        p.ws[i] = v;
        return;
    }
    if (i < F_TOTAL) {
        // node-phase weight frag tables, same packing convention as wb:
        // element j of lane L of frag (kc,nt):  W[32kc+8(L>>4)+j][16nt+(L&15)]
        int x = i - 128;   // 0..61439, each thread writes hi + lo u16
        const float *W; int N, lsh, base, size;
        if (x < 4096)       {             W = p.at_out_w; N = 64;  lsh = 2; base = NW_AOH;  size = 4096;  }
        else if (x < 12288) { x -= 4096;  W = p.ag_w1;    N = 128; lsh = 3; base = NW_AG1H; size = 8192;  }
        else if (x < 28672) { x -= 12288; W = p.ag_w2;    N = 128; lsh = 3; base = NW_AG2H; size = 16384; }
        else                { x -= 28672; W = p.gt_w;     N = 128; lsh = 3; base = NW_GTH;  size = 32768; }
        int j = x & 7, L = (x >> 3) & 63, t = x >> 9;
        int kc = t >> lsh, nt = t & ((1 << lsh) - 1);
        int k = 32 * kc + 8 * (L >> 4) + j;
        int n = 16 * nt + (L & 15);
        float v = W[k * N + n];
        unsigned short h = f2bs(v);
        unsigned short l = f2bs(v - bs2f(h));
        unsigned short *NW = (unsigned short *)(p.ws + F_AOP);
        NW[base + x]        = h;
        NW[base + size + x] = l;
        return;
    }
    int hi = i - F_TOTAL;
    if (hi >= H_TOTAL) return;
    unsigned short *wsh = (unsigned short *)(p.ws + F_TOTAL);
    int base, NT;
    const int region =
        (hi < H_WTS) ? 0 : (hi < H_TS2) ? 1 : (hi < H_MC1) ? 2 :
        (hi < H_WMCE) ? 3 : (hi < H_MC2) ? 4 : (hi < H_ATI) ? 5 : 6;
    switch (region) {
        case 0: base = H_EE1;  NT = 4;  break;
        case 1: base = H_WTS;  NT = 4;  break;
        case 2: base = H_TS2;  NT = 2;  break;
        case 3: base = H_MC1;  NT = 4;  break;
        case 4: base = H_WMCE; NT = 4;  break;
        case 5: base = H_MC2;  NT = 4;  break;
        default: base = H_ATI; NT = 12; break;
    }
    int r0 = hi - base;
    int j  = r0 & 7, L = (r0 >> 3) & 63, tk = r0 >> 9;
    int kc = tk / NT, T = tk - kc * NT;
    int c  = L & 15, gg = L >> 4;
    int k  = 32 * kc + 8 * gg + j;
    int n  = 16 * T + c;
    float v = 0.f;
    switch (region) {
        case 0: v = (k < E_) ? p.ee_w1[k * M_ + n] : 0.f; break;
        case 1: { float s = 0.f;
                  for (int e = 0; e < E_; e++) s += p.ee_w2[k * E_ + e] * p.ts_w1[e * M_ + n];
                  v = s; } break;
        case 2: v = p.ts_w2[k * 32 + n]; break;
        case 3: v = p.mc_w1[k * M_ + n]; break;
        case 4: { float s = 0.f;
                  for (int e = 0; e < E_; e++) s += p.ee_w2[k * E_ + e] * p.mc_w1[(D_ + e) * M_ + n];
                  v = s; } break;
        case 5: v = p.mc_w2[k * M_ + n]; break;
        default: v = p.at_in_w[k * 192 + n]; break;
    }
    wsh[hi] = f2bs(v);
}

// two tasks per wave (A=2i, B=2i+1) through the edge/attention phases
// (barrier-free, per-wave LDS slices), then a BLOCK-COOPERATIVE MFMA node
// phase over the block's 8 tasks.
// LDS shrink for 5 blocks/CU: xp tiles = 15 rows (rows 13/14 garbage; MFMA
// row 15 clamps onto 14), node ping-pong buffers = 8 REAL rows each (MFMA
// A-reads of rows 8..15 alias rows 0..7 via c&7, feeding only discarded
// output rows; writes of output rows 8..15 are skipped with g<2).
// Total: 4*2*15*136*2 = 32,640 B -> 5 blocks/CU (was 34,816 -> 4).
__global__ __launch_bounds__(256) void petri_kernel(Params p) {
    const int tid = threadIdx.x;
    const int w   = tid >> 6;
    const int L   = tid & 63;
    const int c   = L & 15, g = L >> 4;
    const int cr  = (c > 14) ? 14 : c;   // clamped xp read row
    const int c7  = c & 7;               // node-buf read row (8 real rows)
    const int taskA = blockIdx.x * 8 + w * 2;
    const int taskB = taskA + 1;
    const int bsA = taskA / N_, tA = taskA - bsA * N_;
    const int bsB = taskB / N_, tB = taskB - bsB * N_;
    const int mrow = (c < N_) ? c : 0;

    __shared__ __align__(16) unsigned short xp[4][2][15][136];
    unsigned short *xn = &xp[0][0][0][0];
    // node buffers: buf b in [0,2), plane pl in [0,2), 8 rows x 264 u16
    // buf stride 4224 u16 (8448 B), plane stride 2112 u16, row stride 264.
#define XNP(b, pl, r, col) (xn + (b) * 4224 + (pl) * 2112 + (r) * 264 + (col))

    const float *ws = p.ws;
    const v8s *wb = (const v8s *)((const unsigned short *)(ws + F_TOTAL));
    const unsigned short *NW = (const unsigned short *)(ws + F_AOP);
    const v8s zf = {0, 0, 0, 0, 0, 0, 0, 0};

    // =========== E1 (A,B) ===========
    v8s ahA0, ahA1, ahB0, ahB1;
    {
        v8s aA, aB;
        {
            const float *eA = p.edge_features + (((size_t)bsA * N_ + mrow) * N_ + tA) * E_;
            const float *eB = p.edge_features + (((size_t)bsB * N_ + mrow) * N_ + tB) * E_;
            v2f fa = ((const v2f *)eA)[0], fb = ((const v2f *)eA)[1], fc = ((const v2f *)eA)[2];
            v2f ga_ = ((const v2f *)eB)[0], gb = ((const v2f *)eB)[1], gc = ((const v2f *)eB)[2];
            v8s ta = zf, tb = zf;
            ta[0] = (short)f2bs(fa.x); ta[1] = (short)f2bs(fa.y);
            ta[2] = (short)f2bs(fb.x); ta[3] = (short)f2bs(fb.y);
            ta[4] = (short)f2bs(fc.x); ta[5] = (short)f2bs(fc.y);
            tb[0] = (short)f2bs(ga_.x); tb[1] = (short)f2bs(ga_.y);
            tb[2] = (short)f2bs(gb.x); tb[3] = (short)f2bs(gb.y);
            tb[4] = (short)f2bs(gc.x); tb[5] = (short)f2bs(gc.y);
            aA = (g == 0) ? ta : zf;
            aB = (g == 0) ? tb : zf;
        }
        float b0 = p.ee_b1[c], b1 = p.ee_b1[16 + c], b2 = p.ee_b1[32 + c], b3 = p.ee_b1[48 + c];
        v4f h0A = {b0, b0, b0, b0}, h1A = {b1, b1, b1, b1}, h2A = {b2, b2, b2, b2}, h3A = {b3, b3, b3, b3};
        v4f h0B = h0A, h1B = h1A, h2B = h2A, h3B = h3A;
        {
            v8s W0 = wb[0 * 64 + L], W1 = wb[1 * 64 + L], W2 = wb[2 * 64 + L], W3 = wb[3 * 64 + L];
            h0A = MFMA16(aA, W0, h0A); h0B = MFMA16(aB, W0, h0B);
            h1A = MFMA16(aA, W1, h1A); h1B = MFMA16(aB, W1, h1B);
            h2A = MFMA16(aA, W2, h2A); h2B = MFMA16(aB, W2, h2B);
            h3A = MFMA16(aA, W3, h3A); h3B = MFMA16(aB, W3, h3B);
        }
        float lg0 = p.ee_ln_g[c], lg1 = p.ee_ln_g[16 + c], lg2 = p.ee_ln_g[32 + c], lg3 = p.ee_ln_g[48 + c];
        float lb0 = p.ee_ln_b[c], lb1 = p.ee_ln_b[16 + c], lb2 = p.ee_ln_b[32 + c], lb3 = p.ee_ln_b[48 + c];
        ln_c64<true>(h0A, h1A, h2A, h3A, lg0, lg1, lg2, lg3, lb0, lb1, lb2, lb3);
        ln_c64<true>(h0B, h1B, h2B, h3B, lg0, lg1, lg2, lg3, lb0, lb1, lb2, lb3);
        store_c(xp[w][0], 64, L, h0A, h1A, h2A, h3A);
        store_c(xp[w][1], 64, L, h0B, h1B, h2B, h3B);
        LDS_ORDER();
        ahA0 = *(const v8s *)&xp[w][0][cr][64 + 8 * g];
        ahA1 = *(const v8s *)&xp[w][0][cr][96 + 8 * g];
        ahB0 = *(const v8s *)&xp[w][1][cr][64 + 8 * g];
        ahB1 = *(const v8s *)&xp[w][1][cr][96 + 8 * g];
    }

    // =========== TS1 + TS2/3 (A,B) ===========
    v4f tsvA, tsvB;
    {
        float b0 = ws[F_BTS + c], b1 = ws[F_BTS + 16 + c], b2 = ws[F_BTS + 32 + c], b3 = ws[F_BTS + 48 + c];
        v4f t0A = {b0, b0, b0, b0}, t1A = {b1, b1, b1, b1}, t2A = {b2, b2, b2, b2}, t3A = {b3, b3, b3, b3};
        v4f t0B = t0A, t1B = t1A, t2B = t2A, t3B = t3A;
        {
            v8s W;
            W = wb[256 + 0 * 64 + L]; t0A = MFMA16(ahA0, W, t0A); t0B = MFMA16(ahB0, W, t0B);
            W = wb[256 + 4 * 64 + L]; t0A = MFMA16(ahA1, W, t0A); t0B = MFMA16(ahB1, W, t0B);
            W = wb[256 + 1 * 64 + L]; t1A = MFMA16(ahA0, W, t1A); t1B = MFMA16(ahB0, W, t1B);
            W = wb[256 + 5 * 64 + L]; t1A = MFMA16(ahA1, W, t1A); t1B = MFMA16(ahB1, W, t1B);
            W = wb[256 + 2 * 64 + L]; t2A = MFMA16(ahA0, W, t2A); t2B = MFMA16(ahB0, W, t2B);
            W = wb[256 + 6 * 64 + L]; t2A = MFMA16(ahA1, W, t2A); t2B = MFMA16(ahB1, W, t2B);
            W = wb[256 + 3 * 64 + L]; t3A = MFMA16(ahA0, W, t3A); t3B = MFMA16(ahB0, W, t3B);
            W = wb[256 + 7 * 64 + L]; t3A = MFMA16(ahA1, W, t3A); t3B = MFMA16(ahB1, W, t3B);
        }
        float lg0 = p.ts_ln_g[c], lg1 = p.ts_ln_g[16 + c], lg2 = p.ts_ln_g[32 + c], lg3 = p.ts_ln_g[48 + c];
        float lb0 = p.ts_ln_b[c], lb1 = p.ts_ln_b[16 + c], lb2 = p.ts_ln_b[32 + c], lb3 = p.ts_ln_b[48 + c];
        ln_c64<true>(t0A, t1A, t2A, t3A, lg0, lg1, lg2, lg3, lb0, lb1, lb2, lb3);
        ln_c64<true>(t0B, t1B, t2B, t3B, lg0, lg1, lg2, lg3, lb0, lb1, lb2, lb3);
        store_c(xp[w][0], 0, L, t0A, t1A, t2A, t3A);
        store_c(xp[w][1], 0, L, t0B, t1B, t2B, t3B);
        LDS_ORDER();
        v8s atA0 = *(const v8s *)&xp[w][0][cr][0 + 8 * g];
        v8s atA1 = *(const v8s *)&xp[w][0][cr][32 + 8 * g];
        v8s atB0 = *(const v8s *)&xp[w][1][cr][0 + 8 * g];
        v8s atB1 = *(const v8s *)&xp[w][1][cr][32 + 8 * g];
        float u0b = p.ts_b2[c], u1b = p.ts_b2[16 + c];
        v4f u0A = {u0b, u0b, u0b, u0b}, u1A = {u1b, u1b, u1b, u1b};
        v4f u0B = u0A, u1B = u1A;
        {
            v8s W;
            W = wb[768 + 0 * 64 + L]; u0A = MFMA16(atA0, W, u0A); u0B = MFMA16(atB0, W, u0B);
            W = wb[768 + 2 * 64 + L]; u0A = MFMA16(atA1, W, u0A); u0B = MFMA16(atB1, W, u0B);
            W = wb[768 + 1 * 64 + L]; u1A = MFMA16(atA0, W, u1A); u1B = MFMA16(atB0, W, u1B);
            W = wb[768 + 3 * 64 + L]; u1A = MFMA16(atA1, W, u1A); u1B = MFMA16(atB1, W, u1B);
        }
        float w3a = p.ts_w3[c], w3b = p.ts_w3[16 + c], b3v = p.ts_b3[0];
        v4f dA = gelu4(u0A) * w3a + gelu4(u1A) * w3b;
        v4f dB = gelu4(u0B) * w3a + gelu4(u1B) * w3b;
#pragma unroll
        for (int o = 1; o < 16; o <<= 1)
#pragma unroll
            for (int r = 0; r < 4; r++) {
                dA[r] += __shfl_xor(dA[r], o, 64);
                dB[r] += __shfl_xor(dB[r], o, 64);
            }
#pragma unroll
        for (int r = 0; r < 4; r++) {
            tsvA[r] = sigm(dA[r] + b3v);
            tsvB[r] = sigm(dB[r] + b3v);
        }
    }

    // =========== MC1 (A,B) ===========
    v8s amA0, amA1, amB0, amB1;
    {
        float b0 = ws[F_BMC + c], b1 = ws[F_BMC + 16 + c], b2 = ws[F_BMC + 32 + c], b3 = ws[F_BMC + 48 + c];
        v4f m0A = {b0, b0, b0, b0}, m1A = {b1, b1, b1, b1}, m2A = {b2, b2, b2, b2}, m3A = {b3, b3, b3, b3};
        v4f m0B = m0A, m1B = m1A, m2B = m2A, m3B = m3A;
        const float *nsrA = p.node_states + ((size_t)bsA * N_ + mrow) * D_;
        const float *nsrB = p.node_states + ((size_t)bsB * N_ + mrow) * D_;
#pragma unroll
        for (int kc = 0; kc < 4; kc++) {
            v8s anA = pack8(*(const v4f *)(nsrA + 32 * kc + 8 * g),
                            *(const v4f *)(nsrA + 32 * kc + 8 * g + 4));
            v8s anB = pack8(*(const v4f *)(nsrB + 32 * kc + 8 * g),
                            *(const v4f *)(nsrB + 32 * kc + 8 * g + 4));
            v8s W;
            W = wb[1024 + (kc * 4 + 0) * 64 + L]; m0A = MFMA16(anA, W, m0A); m0B = MFMA16(anB, W, m0B);
            W = wb[1024 + (kc * 4 + 1) * 64 + L]; m1A = MFMA16(anA, W, m1A); m1B = MFMA16(anB, W, m1B);
            W = wb[1024 + (kc * 4 + 2) * 64 + L]; m2A = MFMA16(anA, W, m2A); m2B = MFMA16(anB, W, m2B);
            W = wb[1024 + (kc * 4 + 3) * 64 + L]; m3A = MFMA16(anA, W, m3A); m3B = MFMA16(anB, W, m3B);
        }
        {
            v8s W;
            W = wb[2048 + 0 * 64 + L]; m0A = MFMA16(ahA0, W, m0A); m0B = MFMA16(ahB0, W, m0B);
            W = wb[2048 + 4 * 64 + L]; m0A = MFMA16(ahA1, W, m0A); m0B = MFMA16(ahB1, W, m0B);
            W = wb[2048 + 1 * 64 + L]; m1A = MFMA16(ahA0, W, m1A); m1B = MFMA16(ahB0, W, m1B);
            W = wb[2048 + 5 * 64 + L]; m1A = MFMA16(ahA1, W, m1A); m1B = MFMA16(ahB1, W, m1B);
            W = wb[2048 + 2 * 64 + L]; m2A = MFMA16(ahA0, W, m2A); m2B = MFMA16(ahB0, W, m2B);
            W = wb[2048 + 6 * 64 + L]; m2A = MFMA16(ahA1, W, m2A); m2B = MFMA16(ahB1, W, m2B);
            W = wb[2048 + 3 * 64 + L]; m3A = MFMA16(ahA0, W, m3A); m3B = MFMA16(ahB0, W, m3B);
            W = wb[2048 + 7 * 64 + L]; m3A = MFMA16(ahA1, W, m3A); m3B = MFMA16(ahB1, W, m3B);
        }
        float lg0 = p.mc_ln_g[c], lg1 = p.mc_ln_g[16 + c], lg2 = p.mc_ln_g[32 + c], lg3 = p.mc_ln_g[48 + c];
        float lb0 = p.mc_ln_b[c], lb1 = p.mc_ln_b[16 + c], lb2 = p.mc_ln_b[32 + c], lb3 = p.mc_ln_b[48 + c];
        ln_c64<true>(m0A, m1A, m2A, m3A, lg0, lg1, lg2, lg3, lb0, lb1, lb2, lb3);
        ln_c64<true>(m0B, m1B, m2B, m3B, lg0, lg1, lg2, lg3, lb0, lb1, lb2, lb3);
        store_c(xp[w][0], 0, L, m0A, m1A, m2A, m3A);
        store_c(xp[w][1], 0, L, m0B, m1B, m2B, m3B);
        LDS_ORDER();
        amA0 = *(const v8s *)&xp[w][0][cr][0 + 8 * g];
        amA1 = *(const v8s *)&xp[w][0][cr][32 + 8 * g];
        amB0 = *(const v8s *)&xp[w][1][cr][0 + 8 * g];
        amB1 = *(const v8s *)&xp[w][1][cr][32 + 8 * g];
    }

    // =========== MC2 (A,B) ===========
    v8s awA0, awA1, awB0, awB1;
    {
        float b0 = p.mc_b2[c], b1 = p.mc_b2[16 + c], b2 = p.mc_b2[32 + c], b3 = p.mc_b2[48 + c];
        v4f x0A = {b0, b0, b0, b0}, x1A = {b1, b1, b1, b1}, x2A = {b2, b2, b2, b2}, x3A = {b3, b3, b3, b3};
        v4f x0B = x0A, x1B = x1A, x2B = x2A, x3B = x3A;
        {
            v8s W;
            W = wb[2560 + 0 * 64 + L]; x0A = MFMA16(amA0, W, x0A); x0B = MFMA16(amB0, W, x0B);
            W = wb[2560 + 4 * 64 + L]; x0A = MFMA16(amA1, W, x0A); x0B = MFMA16(amB1, W, x0B);
            W = wb[2560 + 1 * 64 + L]; x1A = MFMA16(amA0, W, x1A); x1B = MFMA16(amB0, W, x1B);
            W = wb[2560 + 5 * 64 + L]; x1A = MFMA16(amA1, W, x1A); x1B = MFMA16(amB1, W, x1B);
            W = wb[2560 + 2 * 64 + L]; x2A = MFMA16(amA0, W, x2A); x2B = MFMA16(amB0, W, x2B);
            W = wb[2560 + 6 * 64 + L]; x2A = MFMA16(amA1, W, x2A); x2B = MFMA16(amB1, W, x2B);
            W = wb[2560 + 3 * 64 + L]; x3A = MFMA16(amA0, W, x3A); x3B = MFMA16(amB0, W, x3B);
            W = wb[2560 + 7 * 64 + L]; x3A = MFMA16(amA1, W, x3A); x3B = MFMA16(amB1, W, x3B);
        }
        x0A *= tsvA; x1A *= tsvA; x2A *= tsvA; x3A *= tsvA;
        x0B *= tsvB; x1B *= tsvB; x2B *= tsvB; x3B *= tsvB;
        float lg0 = p.mn_ln_g[c], lg1 = p.mn_ln_g[16 + c], lg2 = p.mn_ln_g[32 + c], lg3 = p.mn_ln_g[48 + c];
        float lb0 = p.mn_ln_b[c], lb1 = p.mn_ln_b[16 + c], lb2 = p.mn_ln_b[32 + c], lb3 = p.mn_ln_b[48 + c];
        ln_c64<false>(x0A, x1A, x2A, x3A, lg0, lg1, lg2, lg3, lb0, lb1, lb2, lb3);
        ln_c64<false>(x0B, x1B, x2B, x3B, lg0, lg1, lg2, lg3, lb0, lb1, lb2, lb3);
        store_c(xp[w][0], 0, L, x0A, x1A, x2A, x3A);
        store_c(xp[w][1], 0, L, x0B, x1B, x2B, x3B);
        LDS_ORDER();
        awA0 = *(const v8s *)&xp[w][0][cr][0 + 8 * g];
        awA1 = *(const v8s *)&xp[w][0][cr][32 + 8 * g];
        awB0 = *(const v8s *)&xp[w][1][cr][0 + 8 * g];
        awB1 = *(const v8s *)&xp[w][1][cr][32 + 8 * g];
    }

    // =========== AT: Q,K stored per-tile; V kept in regs ===========
    v4f vtA0, vtA1, vtA2, vtA3, vtB0, vtB1, vtB2, vtB3;
    {
#define AT_QK(T, DSTC)                                                          \
        { float _b = p.at_in_b[16 * (T) + c];                                    \
          v8s W0 = wb[3072 + (T) * 64 + L], W1 = wb[3072 + (12 + (T)) * 64 + L]; \
          v4f aA = {_b, _b, _b, _b}, aB = aA;                                    \
          aA = MFMA16(awA0, W0, aA); aA = MFMA16(awA1, W1, aA);                  \
          aB = MFMA16(awB0, W0, aB); aB = MFMA16(awB1, W1, aB);                  \
          _Pragma("unroll")                                                      \
          for (int r = 0; r < 4; r++) {                                          \
              int _rr = 4 * g + r; _rr = (_rr > 14) ? 14 : _rr;                  \
              xp[w][0][_rr][(DSTC) + c] = f2bs(aA[r]);                           \
              xp[w][1][_rr][(DSTC) + c] = f2bs(aB[r]);                           \
          } }
        AT_QK(0, 0)  AT_QK(1, 16)  AT_QK(2, 32)  AT_QK(3, 48)
        AT_QK(4, 64) AT_QK(5, 80)  AT_QK(6, 96)  AT_QK(7, 112)
#undef AT_QK
#define AT_V(T, VA, VB)                                                          \
        { float _b = p.at_in_b[16 * (T) + c];                                    \
          v8s W0 = wb[3072 + (T) * 64 + L], W1 = wb[3072 + (12 + (T)) * 64 + L]; \
          VA = (v4f){_b, _b, _b, _b}; VB = VA;                                   \
          VA = MFMA16(awA0, W0, VA); VA = MFMA16(awA1, W1, VA);                  \
          VB = MFMA16(awB0, W0, VB); VB = MFMA16(awB1, W1, VB); }
        AT_V(8, vtA0, vtB0) AT_V(9, vtA1, vtB1) AT_V(10, vtA2, vtB2) AT_V(11, vtA3, vtB3)
#undef AT_V
        LDS_ORDER();
    }

    // =========== attention (A,B) ===========
    float agA0, agA1, agA2, agA3, agB0, agB1, agB2, agB3;
#define ATTN(TI, VT0, VT1, VT2, VT3, O0, O1, O2, O3)                              \
    {                                                                             \
        const v4f z4 = {0.f, 0.f, 0.f, 0.f};                                      \
        v4f s0, s1, s2, s3;                                                       \
        {                                                                         \
            v8s aq, bk;                                                           \
            aq = (g < 2) ? *(const v8s *)&xp[w][TI][cr][0 + 8 * g] : zf;          \
            bk = (g < 2) ? *(const v8s *)&xp[w][TI][cr][64 + 0 + 8 * g] : zf;     \
            s0 = MFMA16(aq, bk, z4);                                              \
            aq = (g < 2) ? *(const v8s *)&xp[w][TI][cr][16 + 8 * g] : zf;         \
            bk = (g < 2) ? *(const v8s *)&xp[w][TI][cr][64 + 16 + 8 * g] : zf;    \
            s1 = MFMA16(aq, bk, z4);                                              \
            aq = (g < 2) ? *(const v8s *)&xp[w][TI][cr][32 + 8 * g] : zf;         \
            bk = (g < 2) ? *(const v8s *)&xp[w][TI][cr][64 + 32 + 8 * g] : zf;    \
            s2 = MFMA16(aq, bk, z4);                                              \
            aq = (g < 2) ? *(const v8s *)&xp[w][TI][cr][48 + 8 * g] : zf;         \
            bk = (g < 2) ? *(const v8s *)&xp[w][TI][cr][64 + 48 + 8 * g] : zf;    \
            s3 = MFMA16(aq, bk, z4);                                              \
        }                                                                         \
        if (c >= N_) {                                                            \
            v4f neg = {-1e30f, -1e30f, -1e30f, -1e30f};                           \
            s0 = neg; s1 = neg; s2 = neg; s3 = neg;                               \
        }                                                                         \
        v4f m0 = s0, m1 = s1, m2 = s2, m3 = s3;                                   \
        _Pragma("unroll")                                                         \
        for (int o = 1; o < 16; o <<= 1)                                          \
            _Pragma("unroll")                                                     \
            for (int r = 0; r < 4; r++) {                                         \
                m0[r] = fmaxf(m0[r], __shfl_xor(m0[r], o, 64));                   \
                m1[r] = fmaxf(m1[r], __shfl_xor(m1[r], o, 64));                   \
                m2[r] = fmaxf(m2[r], __shfl_xor(m2[r], o, 64));                   \
                m3[r] = fmaxf(m3[r], __shfl_xor(m3[r], o, 64));                   \
            }                                                                     \
        v4f e0, e1, e2, e3;                                                       \
        _Pragma("unroll")                                                         \
        for (int r = 0; r < 4; r++) {                                             \
            e0[r] = __expf((s0[r] - m0[r]) * 0.25f);                              \
            e1[r] = __expf((s1[r] - m1[r]) * 0.25f);                              \
            e2[r] = __expf((s2[r] - m2[r]) * 0.25f);                              \
            e3[r] = __expf((s3[r] - m3[r]) * 0.25f);                              \
        }                                                                         \
        v4f z0 = e0, z1 = e1, z2 = e2, z3 = e3;                                   \
        _Pragma("unroll")                                                         \
        for (int o = 1; o < 16; o <<= 1)                                          \
            _Pragma("unroll")                                                     \
            for (int r = 0; r < 4; r++) {                                         \
                z0[r] += __shfl_xor(z0[r], o, 64);                                \
                z1[r] += __shfl_xor(z1[r], o, 64);                                \
                z2[r] += __shfl_xor(z2[r], o, 64);                                \
                z3[r] += __shfl_xor(z3[r], o, 64);                                \
            }                                                                     \
        _Pragma("unroll")                                                         \
        for (int r = 0; r < 4; r++) {                                             \
            e0[r] *= __builtin_amdgcn_rcpf(z0[r]);                                \
            e1[r] *= __builtin_amdgcn_rcpf(z1[r]);                                \
            e2[r] *= __builtin_amdgcn_rcpf(z2[r]);                                \
            e3[r] *= __builtin_amdgcn_rcpf(z3[r]);                                \
        }                                                                         \
        int row0 = 4 * g;                                                         \
        float cs0 = e0[0], cs1 = e1[0], cs2 = e2[0], cs3 = e3[0];                 \
        _Pragma("unroll")                                                         \
        for (int r = 1; r < 4; r++) {                                             \
            bool ok = (row0 + r) < N_;                                            \
            cs0 += ok ? e0[r] : 0.f; cs1 += ok ? e1[r] : 0.f;                     \
            cs2 += ok ? e2[r] : 0.f; cs3 += ok ? e3[r] : 0.f;                     \
        }                                                                         \
        cs0 += __shfl_xor(cs0, 16, 64); cs0 += __shfl_xor(cs0, 32, 64);           \
        cs1 += __shfl_xor(cs1, 16, 64); cs1 += __shfl_xor(cs1, 32, 64);           \
        cs2 += __shfl_xor(cs2, 16, 64); cs2 += __shfl_xor(cs2, 32, 64);           \
        cs3 += __shfl_xor(cs3, 16, 64); cs3 += __shfl_xor(cs3, 32, 64);           \
        int pbase = (((L & 48) + ((L & 48) >> 2)) << 2);                          \
        O0 = 0.f; O1 = 0.f; O2 = 0.f; O3 = 0.f;                                   \
        _Pragma("unroll")                                                         \
        for (int r = 0; r < 4; r++) {                                             \
            int pa = pbase + 4 * r;                                               \
            float c0 = __int_as_float(__builtin_amdgcn_ds_bpermute(pa, __float_as_int(cs0))); \
            float c1 = __int_as_float(__builtin_amdgcn_ds_bpermute(pa, __float_as_int(cs1))); \
            float c2 = __int_as_float(__builtin_amdgcn_ds_bpermute(pa, __float_as_int(cs2))); \
            float c3 = __int_as_float(__builtin_amdgcn_ds_bpermute(pa, __float_as_int(cs3))); \
            O0 += c0 * VT0[r]; O1 += c1 * VT1[r];                                 \
            O2 += c2 * VT2[r]; O3 += c3 * VT3[r];                                 \
        }                                                                         \
        O0 += __shfl_xor(O0, 16, 64); O0 += __shfl_xor(O0, 32, 64);               \
        O1 += __shfl_xor(O1, 16, 64); O1 += __shfl_xor(O1, 32, 64);               \
        O2 += __shfl_xor(O2, 16, 64); O2 += __shfl_xor(O2, 32, 64);               \
        O3 += __shfl_xor(O3, 16, 64); O3 += __shfl_xor(O3, 32, 64);               \
        const float inv13 = 1.0f / 13.0f;                                         \
        O0 *= inv13; O1 *= inv13; O2 *= inv13; O3 *= inv13;                       \
    }
    ATTN(0, vtA0, vtA1, vtA2, vtA3, agA0, agA1, agA2, agA3)
    ATTN(1, vtB0, vtB1, vtB2, vtB3, agB0, agB1, agB2, agB3)
#undef ATTN

    // ============================================================
    // block-cooperative node phase: 8 tasks = MFMA rows 0..7.
    // A-fragment reads of rows 8..15 alias rows 0..7 (c&7) -> feed only
    // discarded output rows; writes of output rows 8..15 skipped (g<2).
    // All operands bf16 hi/lo split, 3-term MFMA product.
    // ============================================================
    const int rA = 2 * w, rB = rA + 1;

    __syncthreads();                 // all waves done with xp (attention)
    if (g == 0) {                    // stage ag -> buf0 rows rA,rB cols 0..63
        wr_hl(XNP(0, 0, rA, c),      XNP(0, 1, rA, c),      agA0);
        wr_hl(XNP(0, 0, rA, 16 + c), XNP(0, 1, rA, 16 + c), agA1);
        wr_hl(XNP(0, 0, rA, 32 + c), XNP(0, 1, rA, 32 + c), agA2);
        wr_hl(XNP(0, 0, rA, 48 + c), XNP(0, 1, rA, 48 + c), agA3);
        wr_hl(XNP(0, 0, rB, c),      XNP(0, 1, rB, c),      agB0);
        wr_hl(XNP(0, 0, rB, 16 + c), XNP(0, 1, rB, 16 + c), agB1);
        wr_hl(XNP(0, 0, rB, 32 + c), XNP(0, 1, rB, 32 + c), agB2);
        wr_hl(XNP(0, 0, rB, 48 + c), XNP(0, 1, rB, 48 + c), agB3);
    }
    __syncthreads();

    // ---- N1: at_out  [8x64] @ [64x64]; wave w owns ntile w; buf0 -> buf1
    {
        const v8s *WH = (const v8s *)(NW + NW_AOH);
        const v8s *WL = (const v8s *)(NW + NW_AOL);
        float bb = p.at_out_b[16 * w + c];
        v4f acc = {bb, bb, bb, bb};
#pragma unroll
        for (int kc = 0; kc < 2; kc++) {
            v8s xh = *(const v8s *)XNP(0, 0, c7, 8 * g + 32 * kc);
            v8s xl = *(const v8s *)XNP(0, 1, c7, 8 * g + 32 * kc);
            v8s wh = WH[(kc * 4 + w) * 64 + L];
            v8s wl = WL[(kc * 4 + w) * 64 + L];
            acc = MFMA16(xh, wl, acc);
            acc = MFMA16(xl, wh, acc);
            acc = MFMA16(xh, wh, acc);
        }
        if (g < 2) {
#pragma unroll
            for (int r = 0; r < 4; r++)
                wr_hl(XNP(1, 0, 4 * g + r, 16 * w + c), XNP(1, 1, 4 * g + r, 16 * w + c), acc[r]);
        }
    }
    __syncthreads();

    // ---- N2: ag1  [8x64] @ [64x128]; wave w owns ntiles 2w,2w+1; buf1 -> buf0
    {
        const v8s *WH = (const v8s *)(NW + NW_AG1H);
        const v8s *WL = (const v8s *)(NW + NW_AG1L);
        const int nt0 = 2 * w, nt1 = nt0 + 1;
        float b0 = p.ag_b1[16 * nt0 + c], b1 = p.ag_b1[16 * nt1 + c];
        v4f a0 = {b0, b0, b0, b0}, a1 = {b1, b1, b1, b1};
#pragma unroll
        for (int kc = 0; kc < 2; kc++) {
            v8s xh = *(const v8s *)XNP(1, 0, c7, 8 * g + 32 * kc);
            v8s xl = *(const v8s *)XNP(1, 1, c7, 8 * g + 32 * kc);
            v8s wh0 = WH[(kc * 8 + nt0) * 64 + L], wl0 = WL[(kc * 8 + nt0) * 64 + L];
            v8s wh1 = WH[(kc * 8 + nt1) * 64 + L], wl1 = WL[(kc * 8 + nt1) * 64 + L];
            a0 = MFMA16(xh, wl0, a0); a1 = MFMA16(xh, wl1, a1);
            a0 = MFMA16(xl, wh0, a0); a1 = MFMA16(xl, wh1, a1);
            a0 = MFMA16(xh, wh0, a0); a1 = MFMA16(xh, wh1, a1);
        }
        if (g < 2) {
#pragma unroll
            for (int r = 0; r < 4; r++) {
                wr_hl(XNP(0, 0, 4 * g + r, 16 * nt0 + c), XNP(0, 1, 4 * g + r, 16 * nt0 + c), a0[r]);
                wr_hl(XNP(0, 0, 4 * g + r, 16 * nt1 + c), XNP(0, 1, 4 * g + r, 16 * nt1 + c), a1[r]);
            }
        }
    }
    __syncthreads();

    // ---- LN+gelu pass: each wave LNs its own 2 tasks; buf0 -> buf1
    {
        float xA0 = bs2f(*XNP(0, 0, rA, L))      + bs2f(*XNP(0, 1, rA, L));
        float xA1 = bs2f(*XNP(0, 0, rA, 64 + L)) + bs2f(*XNP(0, 1, rA, 64 + L));
        float xB0 = bs2f(*XNP(0, 0, rB, L))      + bs2f(*XNP(0, 1, rB, L));
        float xB1 = bs2f(*XNP(0, 0, rB, 64 + L)) + bs2f(*XNP(0, 1, rB, 64 + L));
        float lg0 = p.ag_ln_g[L], lg1 = p.ag_ln_g[L + 64];
        float lb0 = p.ag_ln_b[L], lb1 = p.ag_ln_b[L + 64];
        ln128<true>(xA0, xA1, lg0, lg1, lb0, lb1);
        ln128<true>(xB0, xB1, lg0, lg1, lb0, lb1);
        wr_hl(XNP(1, 0, rA, L),      XNP(1, 1, rA, L),      xA0);
        wr_hl(XNP(1, 0, rA, 64 + L), XNP(1, 1, rA, 64 + L), xA1);
        wr_hl(XNP(1, 0, rB, L),      XNP(1, 1, rB, L),      xB0);
        wr_hl(XNP(1, 0, rB, 64 + L), XNP(1, 1, rB, 64 + L), xB1);
    }
    __syncthreads();

    // ---- N3: ag2  [8x128] @ [128x128] -> ni; buf1 -> buf0 cols 128..255.
    //      also stage node_states (gate cols 0..127) and keep fp32 copies.
    const float *nstA = p.node_states + ((size_t)bsA * N_ + tA) * D_;
    const float *nstB = p.node_states + ((size_t)bsB * N_ + tB) * D_;
    float nA0 = nstA[L], nA1 = nstA[L + 64];
    float nB0 = nstB[L], nB1 = nstB[L + 64];
    {
        const v8s *WH = (const v8s *)(NW + NW_AG2H);
        const v8s *WL = (const v8s *)(NW + NW_AG2L);
        const int nt0 = 2 * w, nt1 = nt0 + 1;
        float b0 = p.ag_b2[16 * nt0 + c], b1 = p.ag_b2[16 * nt1 + c];
        v4f a0 = {b0, b0, b0, b0}, a1 = {b1, b1, b1, b1};
#pragma unroll
        for (int kc = 0; kc < 4; kc++) {
            v8s xh = *(const v8s *)XNP(1, 0, c7, 8 * g + 32 * kc);
            v8s xl = *(const v8s *)XNP(1, 1, c7, 8 * g + 32 * kc);
            v8s wh0 = WH[(kc * 8 + nt0) * 64 + L], wl0 = WL[(kc * 8 + nt0) * 64 + L];
            v8s wh1 = WH[(kc * 8 + nt1) * 64 + L], wl1 = WL[(kc * 8 + nt1) * 64 + L];
            a0 = MFMA16(xh, wl0, a0); a1 = MFMA16(xh, wl1, a1);
            a0 = MFMA16(xl, wh0, a0); a1 = MFMA16(xl, wh1, a1);
            a0 = MFMA16(xh, wh0, a0); a1 = MFMA16(xh, wh1, a1);
        }
        if (g < 2) {
#pragma unroll
            for (int r = 0; r < 4; r++) {
                wr_hl(XNP(0, 0, 4 * g + r, 128 + 16 * nt0 + c), XNP(0, 1, 4 * g + r, 128 + 16 * nt0 + c), a0[r]);
                wr_hl(XNP(0, 0, 4 * g + r, 128 + 16 * nt1 + c), XNP(0, 1, 4 * g + r, 128 + 16 * nt1 + c), a1[r]);
            }
        }
        wr_hl(XNP(0, 0, rA, L),      XNP(0, 1, rA, L),      nA0);
        wr_hl(XNP(0, 0, rA, 64 + L), XNP(0, 1, rA, 64 + L), nA1);
        wr_hl(XNP(0, 0, rB, L),      XNP(0, 1, rB, L),      nB0);
        wr_hl(XNP(0, 0, rB, 64 + L), XNP(0, 1, rB, 64 + L), nB1);
    }
    __syncthreads();

    // ---- N4: gate  [8x256] @ [256x128]; buf0 -> buf1 (gpre)
    {
        const v8s *WH = (const v8s *)(NW + NW_GTH);
        const v8s *WL = (const v8s *)(NW + NW_GTL);
        const int nt0 = 2 * w, nt1 = nt0 + 1;
        float b0 = p.gt_b[16 * nt0 + c], b1 = p.gt_b[16 * nt1 + c];
        v4f a0 = {b0, b0, b0, b0}, a1 = {b1, b1, b1, b1};
#pragma unroll
        for (int kc = 0; kc < 8; kc++) {
            v8s xh = *(const v8s *)XNP(0, 0, c7, 8 * g + 32 * kc);
            v8s xl = *(const v8s *)XNP(0, 1, c7, 8 * g + 32 * kc);
            v8s wh0 = WH[(kc * 8 + nt0) * 64 + L], wl0 = WL[(kc * 8 + nt0) * 64 + L];
            v8s wh1 = WH[(kc * 8 + nt1) * 64 + L], wl1 = WL[(kc * 8 + nt1) * 64 + L];
            a0 = MFMA16(xh, wl0, a0); a1 = MFMA16(xh, wl1, a1);
            a0 = MFMA16(xl, wh0, a0); a1 = MFMA16(xl, wh1, a1);
            a0 = MFMA16(xh, wh0, a0); a1 = MFMA16(xh, wh1, a1);
        }
        if (g < 2) {
#pragma unroll
            for (int r = 0; r < 4; r++) {
                wr_hl(XNP(1, 0, 4 * g + r, 16 * nt0 + c), XNP(1, 1, 4 * g + r, 16 * nt0 + c), a0[r]);
                wr_hl(XNP(1, 0, 4 * g + r, 16 * nt1 + c), XNP(1, 1, 4 * g + r, 16 * nt1 + c), a1[r]);
            }
        }
    }
    __syncthreads();

    // ---- final: sigmoid gate, update, node LN, store
    {
        float gpA0 = bs2f(*XNP(1, 0, rA, L))      + bs2f(*XNP(1, 1, rA, L));
        float gpA1 = bs2f(*XNP(1, 0, rA, 64 + L)) + bs2f(*XNP(1, 1, rA, 64 + L));
        float gpB0 = bs2f(*XNP(1, 0, rB, L))      + bs2f(*XNP(1, 1, rB, L));
        float gpB1 = bs2f(*XNP(1, 0, rB, 64 + L)) + bs2f(*XNP(1, 1, rB, 64 + L));
        float niA0 = bs2f(*XNP(0, 0, rA, 128 + L)) + bs2f(*XNP(0, 1, rA, 128 + L));
        float niA1 = bs2f(*XNP(0, 0, rA, 192 + L)) + bs2f(*XNP(0, 1, rA, 192 + L));
        float niB0 = bs2f(*XNP(0, 0, rB, 128 + L)) + bs2f(*XNP(0, 1, rB, 128 + L));
        float niB1 = bs2f(*XNP(0, 0, rB, 192 + L)) + bs2f(*XNP(0, 1, rB, 192 + L));
        float gA0 = sigm(gpA0), gA1 = sigm(gpA1);
        float gB0 = sigm(gpB0), gB1 = sigm(gpB1);
        float updA0 = gA0 * niA0 + (1.f - gA0) * nA0;
        float updA1 = gA1 * niA1 + (1.f - gA1) * nA1;
        float updB0 = gB0 * niB0 + (1.f - gB0) * nB0;
        float updB1 = gB1 * niB1 + (1.f - gB1) * nB1;
        float lg0 = p.nn_ln_g[L], lg1 = p.nn_ln_g[L + 64];
        float lb0 = p.nn_ln_b[L], lb1 = p.nn_ln_b[L + 64];
        ln128<false>(updA0, updA1, lg0, lg1, lb0, lb1);
        ln128<false>(updB0, updB1, lg0, lg1, lb0, lb1);
        float *opA = p.out + ((size_t)bsA * N_ + tA) * D_;
        float *opB = p.out + ((size_t)bsB * N_ + tB) * D_;
        opA[L] = updA0; opA[L + 64] = updA1;
        opB[L] = updB0; opB[L + 64] = updB1;
    }
#undef XNP
}

extern "C" void kernel_launch(void* const* d_in, const int* in_sizes, int n_in,
                              void* d_out, int out_size, void* d_ws, size_t ws_size,
                              hipStream_t stream) {
    Params p;
    p.node_states   = (const float*)d_in[0];
    p.edge_features = (const float*)d_in[1];
    p.ee_w1   = (const float*)d_in[2];
    p.ee_b1   = (const float*)d_in[3];
    p.ee_ln_g = (const float*)d_in[4];
    p.ee_ln_b = (const float*)d_in[5];
    p.ee_w2   = (const float*)d_in[6];
    p.ee_b2   = (const float*)d_in[7];
    p.ts_w1   = (const float*)d_in[8];
    p.ts_b1   = (const float*)d_in[9];
    p.ts_ln_g = (const float*)d_in[10];
    p.ts_ln_b = (const float*)d_in[11];
    p.ts_w2   = (const float*)d_in[12];
    p.ts_b2   = (const float*)d_in[13];
    p.ts_w3   = (const float*)d_in[14];
    p.ts_b3   = (const float*)d_in[15];
    p.mc_w1   = (const float*)d_in[16];
    p.mc_b1   = (const float*)d_in[17];
    p.mc_ln_g = (const float*)d_in[18];
    p.mc_ln_b = (const float*)d_in[19];
    p.mc_w2   = (const float*)d_in[20];
    p.mc_b2   = (const float*)d_in[21];
    p.at_in_w  = (const float*)d_in[22];
    p.at_in_b  = (const float*)d_in[23];
    p.at_out_w = (const float*)d_in[24];
    p.at_out_b = (const float*)d_in[25];
    p.ag_w1   = (const float*)d_in[26];
    p.ag_b1   = (const float*)d_in[27];
    p.ag_ln_g = (const float*)d_in[28];
    p.ag_ln_b = (const float*)d_in[29];
    p.ag_w2   = (const float*)d_in[30];
    p.ag_b2   = (const float*)d_in[31];
    p.gt_w    = (const float*)d_in[32];
    p.gt_b    = (const float*)d_in[33];
    p.nn_ln_g = (const float*)d_in[34];
    p.nn_ln_b = (const float*)d_in[35];
    p.mn_ln_g = (const float*)d_in[36];
    p.mn_ln_b = (const float*)d_in[37];
    p.ws      = (float*)d_ws;
    p.out     = (float*)d_out;

    const int prep_threads = F_TOTAL + H_TOTAL;
    hipLaunchKernelGGL(prep_kernel, dim3((prep_threads + 255) / 256), dim3(256), 0, stream, p);
    hipLaunchKernelGGL(petri_kernel, dim3((B_ * S_ * N_) / 8), dim3(256), 0, stream, p);
}

// Round 4
// 345.434 us; speedup vs baseline: 1.0535x; 1.0535x over previous
//
#include <hip/hip_runtime.h>

#define B_  16
#define S_  128
#define N_  13
#define D_  128
#define E_  6
#define M_  64
#define H_  4

typedef float v2f __attribute__((ext_vector_type(2)));
typedef float v4f __attribute__((ext_vector_type(4)));
typedef short v8s __attribute__((ext_vector_type(8)));

#define MFMA16(A, B, C) __builtin_amdgcn_mfma_f32_16x16x32_bf16((A), (B), (C), 0, 0, 0)
#define LDS_ORDER() __asm__ __volatile__("" ::: "memory")

#if __has_builtin(__builtin_elementwise_fma)
#define PKFMA(A, B, C) __builtin_elementwise_fma((A), (B), (C))
#else
#define PKFMA(A, B, C) ((A) * (B) + (C))
#endif
#define LO2(X) __builtin_shufflevector((X), (X), 0, 1)
#define HI2(X) __builtin_shufflevector((X), (X), 2, 3)

// ---- workspace layout ----
#define F_BTS   0
#define F_BMC   64
#define F_AOP   128
#define F_TOTAL 61568
#define NW_AOH  0
#define NW_AOL  4096
#define NW_AG1H 8192
#define NW_AG1L 16384
#define NW_AG2H 24576
#define NW_AG2L 40960
#define NW_GTH  57344
#define NW_GTL  90112
#define H_EE1   0
#define H_WTS   2048
#define H_TS2   6144
#define H_MC1   8192
#define H_WMCE  16384
#define H_MC2   20480
#define H_ATI   24576
#define H_TOTAL 36864

__device__ __forceinline__ unsigned short f2bs(float x) {  // RTNE fp32->bf16 (prep only)
    unsigned u = __float_as_uint(x);
    u += 0x7FFFu + ((u >> 16) & 1u);
    return (unsigned short)(u >> 16);
}
__device__ __forceinline__ float bs2f(unsigned short h) {
    return __uint_as_float((unsigned)h << 16);
}
// hardware packed bf16 convert (RTNE): lo16 = bf16(a), hi16 = bf16(b)
__device__ __forceinline__ unsigned cvtpk(float a, float b) {
    unsigned r;
    asm("v_cvt_pk_bf16_f32 %0, %1, %2" : "=v"(r) : "v"(a), "v"(b));
    return r;
}

__device__ __forceinline__ float sigm(float x) { return 1.0f / (1.0f + __expf(-x)); }

__device__ __forceinline__ v2f splat2(float v) { v2f r; r.x = v; r.y = v; return r; }

// packed-f32 exact-erf GELU (A&S 7.1.26 poly, |eps|<1.5e-7); v_pk_fma for the chain
__device__ __forceinline__ v2f gelu2(v2f x) {
    const v2f one  = splat2(1.f);
    const v2f c_a  = splat2(0.3275911f);
    const v2f c_p4 = splat2(1.061405429f);
    const v2f c_p3 = splat2(-1.453152027f);
    const v2f c_p2 = splat2(1.421413741f);
    const v2f c_p1 = splat2(-0.284496736f);
    const v2f c_p0 = splat2(0.254829592f);
    v2f y = x * 0.70710678118654752f;
    v2f ay; ay.x = fabsf(y.x); ay.y = fabsf(y.y);
    v2f t;
    {
        v2f d = PKFMA(ay, c_a, one);
        t.x = __builtin_amdgcn_rcpf(d.x);
        t.y = __builtin_amdgcn_rcpf(d.y);
    }
    v2f pp = PKFMA(t, c_p4, c_p3);
    pp = PKFMA(t, pp, c_p2);
    pp = PKFMA(t, pp, c_p1);
    pp = PKFMA(t, pp, c_p0);
    pp = pp * t;
    v2f e; e.x = __expf(-(ay.x * ay.x)); e.y = __expf(-(ay.y * ay.y));
    v2f er = PKFMA(-pp, e, one);
    er.x = copysignf(er.x, y.x); er.y = copysignf(er.y, y.y);
    v2f hx = x * 0.5f;
    return PKFMA(hx, er, hx);
}
__device__ __forceinline__ v4f gelu4(v4f x) {
    v2f lo = gelu2(LO2(x));
    v2f hi = gelu2(HI2(x));
    return __builtin_shufflevector(lo, hi, 0, 1, 2, 3);
}

template <bool DOGELU>
__device__ __forceinline__ void ln_c64(v4f &a0, v4f &a1, v4f &a2, v4f &a3,
                                       float g0, float g1, float g2, float g3,
                                       float b0, float b1, float b2, float b3) {
    v4f s = a0 + a1 + a2 + a3;
    v4f q = a0 * a0 + a1 * a1 + a2 * a2 + a3 * a3;
#pragma unroll
    for (int o = 1; o < 16; o <<= 1) {
#pragma unroll
        for (int r = 0; r < 4; r++) {
            s[r] += __shfl_xor(s[r], o, 64);
            q[r] += __shfl_xor(q[r], o, 64);
        }
    }
    v4f mean = s * 0.015625f;
    v4f rs;
#pragma unroll
    for (int r = 0; r < 4; r++) {
        float var = fmaxf(q[r] * 0.015625f - mean[r] * mean[r], 0.f);
        rs[r] = rsqrtf(var + 1e-5f);
    }
    a0 = (a0 - mean) * rs * g0 + b0;
    a1 = (a1 - mean) * rs * g1 + b1;
    a2 = (a2 - mean) * rs * g2 + b2;
    a3 = (a3 - mean) * rs * g3 + b3;
    if (DOGELU) { a0 = gelu4(a0); a1 = gelu4(a1); a2 = gelu4(a2); a3 = gelu4(a3); }
}

template <bool DOGELU>
__device__ __forceinline__ void ln128(float &x0, float &x1, float g0_, float g1_,
                                      float b0_, float b1_) {
    float s = x0 + x1, q = x0 * x0 + x1 * x1;
#pragma unroll
    for (int o = 1; o < 64; o <<= 1) { s += __shfl_xor(s, o, 64); q += __shfl_xor(q, o, 64); }
    float mean = s * (1.f / 128.f);
    float var  = fmaxf(q * (1.f / 128.f) - mean * mean, 0.f);
    float rs   = rsqrtf(var + 1e-5f);
    x0 = (x0 - mean) * rs * g0_ + b0_;
    x1 = (x1 - mean) * rs * g1_ + b1_;
    if (DOGELU) {
        v2f xx; xx.x = x0; xx.y = x1;
        v2f gg = gelu2(xx); x0 = gg.x; x1 = gg.y;
    }
}

__device__ __forceinline__ void store_c(unsigned short (*xr)[136], int colbase, int L,
                                        v4f a0, v4f a1, v4f a2, v4f a3) {
    const int c = L & 15, g = L >> 4;
#pragma unroll
    for (int r = 0; r < 4; r++) {
        unsigned u01 = cvtpk(a0[r], a1[r]);
        unsigned u23 = cvtpk(a2[r], a3[r]);
        xr[4 * g + r][colbase + c]      = (unsigned short)u01;
        xr[4 * g + r][colbase + 16 + c] = (unsigned short)(u01 >> 16);
        xr[4 * g + r][colbase + 32 + c] = (unsigned short)u23;
        xr[4 * g + r][colbase + 48 + c] = (unsigned short)(u23 >> 16);
    }
}

__device__ __forceinline__ v8s pack8(v4f lo, v4f hi) {
    union { unsigned u[4]; v8s v; } r;
    r.u[0] = cvtpk(lo[0], lo[1]);
    r.u[1] = cvtpk(lo[2], lo[3]);
    r.u[2] = cvtpk(hi[0], hi[1]);
    r.u[3] = cvtpk(hi[2], hi[3]);
    return r.v;
}

// hi/lo split write of a PAIR of values (cvt_pk based)
__device__ __forceinline__ void wr_hl2(unsigned short *ph0, unsigned short *pl0, float v0,
                                       unsigned short *ph1, unsigned short *pl1, float v1) {
    unsigned h = cvtpk(v0, v1);
    float r0 = v0 - __uint_as_float(h << 16);
    float r1 = v1 - __uint_as_float(h & 0xFFFF0000u);
    unsigned l = cvtpk(r0, r1);
    *ph0 = (unsigned short)h;  *ph1 = (unsigned short)(h >> 16);
    *pl0 = (unsigned short)l;  *pl1 = (unsigned short)(l >> 16);
}

struct Params {
    const float *node_states, *edge_features;
    const float *ee_w1, *ee_b1, *ee_ln_g, *ee_ln_b, *ee_w2, *ee_b2;
    const float *ts_w1, *ts_b1, *ts_ln_g, *ts_ln_b, *ts_w2, *ts_b2, *ts_w3, *ts_b3;
    const float *mc_w1, *mc_b1, *mc_ln_g, *mc_ln_b, *mc_w2, *mc_b2;
    const float *at_in_w, *at_in_b, *at_out_w, *at_out_b;
    const float *ag_w1, *ag_b1, *ag_ln_g, *ag_ln_b, *ag_w2, *ag_b2;
    const float *gt_w, *gt_b, *nn_ln_g, *nn_ln_b, *mn_ln_g, *mn_ln_b;
    float *ws;
    float *out;
};

__global__ __launch_bounds__(256) void prep_kernel(Params p) {
    int i = blockIdx.x * 256 + threadIdx.x;
    if (i < 128) {   // folded biases
        float v;
        if (i < F_BMC) {
            int o = i - F_BTS;
            float s = p.ts_b1[o];
            for (int e = 0; e < E_; e++) s += p.ee_b2[e] * p.ts_w1[e * M_ + o];
            v = s;
        } else {
            int o = i - F_BMC;
            float s = p.mc_b1[o];
            for (int e = 0; e < E_; e++) s += p.ee_b2[e] * p.mc_w1[(D_ + e) * M_ + o];
            v = s;
        }
        p.ws[i] = v;
        return;
    }
    if (i < F_TOTAL) {
        int x = i - 128;
        const float *W; int N, lsh, base, size;
        if (x < 4096)       {             W = p.at_out_w; N = 64;  lsh = 2; base = NW_AOH;  size = 4096;  }
        else if (x < 12288) { x -= 4096;  W = p.ag_w1;    N = 128; lsh = 3; base = NW_AG1H; size = 8192;  }
        else if (x < 28672) { x -= 12288; W = p.ag_w2;    N = 128; lsh = 3; base = NW_AG2H; size = 16384; }
        else                { x -= 28672; W = p.gt_w;     N = 128; lsh = 3; base = NW_GTH;  size = 32768; }
        int j = x & 7, L = (x >> 3) & 63, t = x >> 9;
        int kc = t >> lsh, nt = t & ((1 << lsh) - 1);
        int k = 32 * kc + 8 * (L >> 4) + j;
        int n = 16 * nt + (L & 15);
        float v = W[k * N + n];
        unsigned short h = f2bs(v);
        unsigned short l = f2bs(v - bs2f(h));
        unsigned short *NW = (unsigned short *)(p.ws + F_AOP);
        NW[base + x]        = h;
        NW[base + size + x] = l;
        return;
    }
    int hi = i - F_TOTAL;
    if (hi >= H_TOTAL) return;
    unsigned short *wsh = (unsigned short *)(p.ws + F_TOTAL);
    int base, NT;
    const int region =
        (hi < H_WTS) ? 0 : (hi < H_TS2) ? 1 : (hi < H_MC1) ? 2 :
        (hi < H_WMCE) ? 3 : (hi < H_MC2) ? 4 : (hi < H_ATI) ? 5 : 6;
    switch (region) {
        case 0: base = H_EE1;  NT = 4;  break;
        case 1: base = H_WTS;  NT = 4;  break;
        case 2: base = H_TS2;  NT = 2;  break;
        case 3: base = H_MC1;  NT = 4;  break;
        case 4: base = H_WMCE; NT = 4;  break;
        case 5: base = H_MC2;  NT = 4;  break;
        default: base = H_ATI; NT = 12; break;
    }
    int r0 = hi - base;
    int j  = r0 & 7, L = (r0 >> 3) & 63, tk = r0 >> 9;
    int kc = tk / NT, T = tk - kc * NT;
    int c  = L & 15, gg = L >> 4;
    int k  = 32 * kc + 8 * gg + j;
    int n  = 16 * T + c;
    float v = 0.f;
    switch (region) {
        case 0: v = (k < E_) ? p.ee_w1[k * M_ + n] : 0.f; break;
        case 1: { float s = 0.f;
                  for (int e = 0; e < E_; e++) s += p.ee_w2[k * E_ + e] * p.ts_w1[e * M_ + n];
                  v = s; } break;
        case 2: v = p.ts_w2[k * 32 + n]; break;
        case 3: v = p.mc_w1[k * M_ + n]; break;
        case 4: { float s = 0.f;
                  for (int e = 0; e < E_; e++) s += p.ee_w2[k * E_ + e] * p.mc_w1[(D_ + e) * M_ + n];
                  v = s; } break;
        case 5: v = p.mc_w2[k * M_ + n]; break;
        default: v = p.at_in_w[k * 192 + n]; break;
    }
    wsh[hi] = f2bs(v);
}

// two tasks per wave (A=2i, B=2i+1) through the edge/attention phases
// (barrier-free, per-wave LDS slices), then a BLOCK-COOPERATIVE MFMA node
// phase over the block's 8 tasks.  Node output rows 8..15 are garbage: their
// writes are skipped (g<2); stale A-rows only feed discarded C-rows.
__global__ __launch_bounds__(256) void petri_kernel(Params p) {
    const int tid = threadIdx.x;
    const int w   = tid >> 6;
    const int L   = tid & 63;
    const int c   = L & 15, g = L >> 4;
    const int taskA = blockIdx.x * 8 + w * 2;
    const int taskB = taskA + 1;
    const int bsA = taskA / N_, tA = taskA - bsA * N_;
    const int bsB = taskB / N_, tB = taskB - bsB * N_;
    const int mrow = (c < N_) ? c : 0;

    __shared__ __align__(16) unsigned short xp[4][2][16][136];
    unsigned short *xn = &xp[0][0][0][0];
#define XNP(b, pl, r, col) (xn + (b) * 8448 + (pl) * 4224 + (r) * 264 + (col))

    const float *ws = p.ws;
    const v8s *wb = (const v8s *)((const unsigned short *)(ws + F_TOTAL));
    const unsigned short *NW = (const unsigned short *)(ws + F_AOP);
    const v8s zf = {0, 0, 0, 0, 0, 0, 0, 0};

    // =========== E1 (A,B) ===========
    v8s ahA0, ahA1, ahB0, ahB1;
    {
        v8s aA, aB;
        {
            const float *eA = p.edge_features + (((size_t)bsA * N_ + mrow) * N_ + tA) * E_;
            const float *eB = p.edge_features + (((size_t)bsB * N_ + mrow) * N_ + tB) * E_;
            v2f fa = ((const v2f *)eA)[0], fb = ((const v2f *)eA)[1], fc = ((const v2f *)eA)[2];
            v2f ga_ = ((const v2f *)eB)[0], gb = ((const v2f *)eB)[1], gc = ((const v2f *)eB)[2];
            union { unsigned u[4]; v8s v; } ta, tb;
            ta.u[0] = cvtpk(fa.x, fa.y); ta.u[1] = cvtpk(fb.x, fb.y);
            ta.u[2] = cvtpk(fc.x, fc.y); ta.u[3] = 0;
            tb.u[0] = cvtpk(ga_.x, ga_.y); tb.u[1] = cvtpk(gb.x, gb.y);
            tb.u[2] = cvtpk(gc.x, gc.y); tb.u[3] = 0;
            aA = (g == 0) ? ta.v : zf;
            aB = (g == 0) ? tb.v : zf;
        }
        float b0 = p.ee_b1[c], b1 = p.ee_b1[16 + c], b2 = p.ee_b1[32 + c], b3 = p.ee_b1[48 + c];
        v4f h0A = {b0, b0, b0, b0}, h1A = {b1, b1, b1, b1}, h2A = {b2, b2, b2, b2}, h3A = {b3, b3, b3, b3};
        v4f h0B = h0A, h1B = h1A, h2B = h2A, h3B = h3A;
        {
            v8s W0 = wb[0 * 64 + L], W1 = wb[1 * 64 + L], W2 = wb[2 * 64 + L], W3 = wb[3 * 64 + L];
            h0A = MFMA16(aA, W0, h0A); h0B = MFMA16(aB, W0, h0B);
            h1A = MFMA16(aA, W1, h1A); h1B = MFMA16(aB, W1, h1B);
            h2A = MFMA16(aA, W2, h2A); h2B = MFMA16(aB, W2, h2B);
            h3A = MFMA16(aA, W3, h3A); h3B = MFMA16(aB, W3, h3B);
        }
        float lg0 = p.ee_ln_g[c], lg1 = p.ee_ln_g[16 + c], lg2 = p.ee_ln_g[32 + c], lg3 = p.ee_ln_g[48 + c];
        float lb0 = p.ee_ln_b[c], lb1 = p.ee_ln_b[16 + c], lb2 = p.ee_ln_b[32 + c], lb3 = p.ee_ln_b[48 + c];
        ln_c64<true>(h0A, h1A, h2A, h3A, lg0, lg1, lg2, lg3, lb0, lb1, lb2, lb3);
        ln_c64<true>(h0B, h1B, h2B, h3B, lg0, lg1, lg2, lg3, lb0, lb1, lb2, lb3);
        store_c(xp[w][0], 64, L, h0A, h1A, h2A, h3A);
        store_c(xp[w][1], 64, L, h0B, h1B, h2B, h3B);
        LDS_ORDER();
        ahA0 = *(const v8s *)&xp[w][0][c][64 + 8 * g];
        ahA1 = *(const v8s *)&xp[w][0][c][96 + 8 * g];
        ahB0 = *(const v8s *)&xp[w][1][c][64 + 8 * g];
        ahB1 = *(const v8s *)&xp[w][1][c][96 + 8 * g];
    }

    // =========== TS1 + TS2/3 (A,B) ===========
    v4f tsvA, tsvB;
    {
        float b0 = ws[F_BTS + c], b1 = ws[F_BTS + 16 + c], b2 = ws[F_BTS + 32 + c], b3 = ws[F_BTS + 48 + c];
        v4f t0A = {b0, b0, b0, b0}, t1A = {b1, b1, b1, b1}, t2A = {b2, b2, b2, b2}, t3A = {b3, b3, b3, b3};
        v4f t0B = t0A, t1B = t1A, t2B = t2A, t3B = t3A;
        {
            v8s W;
            W = wb[256 + 0 * 64 + L]; t0A = MFMA16(ahA0, W, t0A); t0B = MFMA16(ahB0, W, t0B);
            W = wb[256 + 4 * 64 + L]; t0A = MFMA16(ahA1, W, t0A); t0B = MFMA16(ahB1, W, t0B);
            W = wb[256 + 1 * 64 + L]; t1A = MFMA16(ahA0, W, t1A); t1B = MFMA16(ahB0, W, t1B);
            W = wb[256 + 5 * 64 + L]; t1A = MFMA16(ahA1, W, t1A); t1B = MFMA16(ahB1, W, t1B);
            W = wb[256 + 2 * 64 + L]; t2A = MFMA16(ahA0, W, t2A); t2B = MFMA16(ahB0, W, t2B);
            W = wb[256 + 6 * 64 + L]; t2A = MFMA16(ahA1, W, t2A); t2B = MFMA16(ahB1, W, t2B);
            W = wb[256 + 3 * 64 + L]; t3A = MFMA16(ahA0, W, t3A); t3B = MFMA16(ahB0, W, t3B);
            W = wb[256 + 7 * 64 + L]; t3A = MFMA16(ahA1, W, t3A); t3B = MFMA16(ahB1, W, t3B);
        }
        float lg0 = p.ts_ln_g[c], lg1 = p.ts_ln_g[16 + c], lg2 = p.ts_ln_g[32 + c], lg3 = p.ts_ln_g[48 + c];
        float lb0 = p.ts_ln_b[c], lb1 = p.ts_ln_b[16 + c], lb2 = p.ts_ln_b[32 + c], lb3 = p.ts_ln_b[48 + c];
        ln_c64<true>(t0A, t1A, t2A, t3A, lg0, lg1, lg2, lg3, lb0, lb1, lb2, lb3);
        ln_c64<true>(t0B, t1B, t2B, t3B, lg0, lg1, lg2, lg3, lb0, lb1, lb2, lb3);
        store_c(xp[w][0], 0, L, t0A, t1A, t2A, t3A);
        store_c(xp[w][1], 0, L, t0B, t1B, t2B, t3B);
        LDS_ORDER();
        v8s atA0 = *(const v8s *)&xp[w][0][c][0 + 8 * g];
        v8s atA1 = *(const v8s *)&xp[w][0][c][32 + 8 * g];
        v8s atB0 = *(const v8s *)&xp[w][1][c][0 + 8 * g];
        v8s atB1 = *(const v8s *)&xp[w][1][c][32 + 8 * g];
        float u0b = p.ts_b2[c], u1b = p.ts_b2[16 + c];
        v4f u0A = {u0b, u0b, u0b, u0b}, u1A = {u1b, u1b, u1b, u1b};
        v4f u0B = u0A, u1B = u1A;
        {
            v8s W;
            W = wb[768 + 0 * 64 + L]; u0A = MFMA16(atA0, W, u0A); u0B = MFMA16(atB0, W, u0B);
            W = wb[768 + 2 * 64 + L]; u0A = MFMA16(atA1, W, u0A); u0B = MFMA16(atB1, W, u0B);
            W = wb[768 + 1 * 64 + L]; u1A = MFMA16(atA0, W, u1A); u1B = MFMA16(atB0, W, u1B);
            W = wb[768 + 3 * 64 + L]; u1A = MFMA16(atA1, W, u1A); u1B = MFMA16(atB1, W, u1B);
        }
        float w3a = p.ts_w3[c], w3b = p.ts_w3[16 + c], b3v = p.ts_b3[0];
        v4f dA = gelu4(u0A) * w3a + gelu4(u1A) * w3b;
        v4f dB = gelu4(u0B) * w3a + gelu4(u1B) * w3b;
#pragma unroll
        for (int o = 1; o < 16; o <<= 1)
#pragma unroll
            for (int r = 0; r < 4; r++) {
                dA[r] += __shfl_xor(dA[r], o, 64);
                dB[r] += __shfl_xor(dB[r], o, 64);
            }
#pragma unroll
        for (int r = 0; r < 4; r++) {
            tsvA[r] = sigm(dA[r] + b3v);
            tsvB[r] = sigm(dB[r] + b3v);
        }
    }

    // =========== MC1 (A,B) ===========
    v8s amA0, amA1, amB0, amB1;
    {
        float b0 = ws[F_BMC + c], b1 = ws[F_BMC + 16 + c], b2 = ws[F_BMC + 32 + c], b3 = ws[F_BMC + 48 + c];
        v4f m0A = {b0, b0, b0, b0}, m1A = {b1, b1, b1, b1}, m2A = {b2, b2, b2, b2}, m3A = {b3, b3, b3, b3};
        v4f m0B = m0A, m1B = m1A, m2B = m2A, m3B = m3A;
        const float *nsrA = p.node_states + ((size_t)bsA * N_ + mrow) * D_;
        const float *nsrB = p.node_states + ((size_t)bsB * N_ + mrow) * D_;
#pragma unroll
        for (int kc = 0; kc < 4; kc++) {
            v8s anA = pack8(*(const v4f *)(nsrA + 32 * kc + 8 * g),
                            *(const v4f *)(nsrA + 32 * kc + 8 * g + 4));
            v8s anB = pack8(*(const v4f *)(nsrB + 32 * kc + 8 * g),
                            *(const v4f *)(nsrB + 32 * kc + 8 * g + 4));
            v8s W;
            W = wb[1024 + (kc * 4 + 0) * 64 + L]; m0A = MFMA16(anA, W, m0A); m0B = MFMA16(anB, W, m0B);
            W = wb[1024 + (kc * 4 + 1) * 64 + L]; m1A = MFMA16(anA, W, m1A); m1B = MFMA16(anB, W, m1B);
            W = wb[1024 + (kc * 4 + 2) * 64 + L]; m2A = MFMA16(anA, W, m2A); m2B = MFMA16(anB, W, m2B);
            W = wb[1024 + (kc * 4 + 3) * 64 + L]; m3A = MFMA16(anA, W, m3A); m3B = MFMA16(anB, W, m3B);
        }
        {
            v8s W;
            W = wb[2048 + 0 * 64 + L]; m0A = MFMA16(ahA0, W, m0A); m0B = MFMA16(ahB0, W, m0B);
            W = wb[2048 + 4 * 64 + L]; m0A = MFMA16(ahA1, W, m0A); m0B = MFMA16(ahB1, W, m0B);
            W = wb[2048 + 1 * 64 + L]; m1A = MFMA16(ahA0, W, m1A); m1B = MFMA16(ahB0, W, m1B);
            W = wb[2048 + 5 * 64 + L]; m1A = MFMA16(ahA1, W, m1A); m1B = MFMA16(ahB1, W, m1B);
            W = wb[2048 + 2 * 64 + L]; m2A = MFMA16(ahA0, W, m2A); m2B = MFMA16(ahB0, W, m2B);
            W = wb[2048 + 6 * 64 + L]; m2A = MFMA16(ahA1, W, m2A); m2B = MFMA16(ahB1, W, m2B);
            W = wb[2048 + 3 * 64 + L]; m3A = MFMA16(ahA0, W, m3A); m3B = MFMA16(ahB0, W, m3B);
            W = wb[2048 + 7 * 64 + L]; m3A = MFMA16(ahA1, W, m3A); m3B = MFMA16(ahB1, W, m3B);
        }
        float lg0 = p.mc_ln_g[c], lg1 = p.mc_ln_g[16 + c], lg2 = p.mc_ln_g[32 + c], lg3 = p.mc_ln_g[48 + c];
        float lb0 = p.mc_ln_b[c], lb1 = p.mc_ln_b[16 + c], lb2 = p.mc_ln_b[32 + c], lb3 = p.mc_ln_b[48 + c];
        ln_c64<true>(m0A, m1A, m2A, m3A, lg0, lg1, lg2, lg3, lb0, lb1, lb2, lb3);
        ln_c64<true>(m0B, m1B, m2B, m3B, lg0, lg1, lg2, lg3, lb0, lb1, lb2, lb3);
        store_c(xp[w][0], 0, L, m0A, m1A, m2A, m3A);
        store_c(xp[w][1], 0, L, m0B, m1B, m2B, m3B);
        LDS_ORDER();
        amA0 = *(const v8s *)&xp[w][0][c][0 + 8 * g];
        amA1 = *(const v8s *)&xp[w][0][c][32 + 8 * g];
        amB0 = *(const v8s *)&xp[w][1][c][0 + 8 * g];
        amB1 = *(const v8s *)&xp[w][1][c][32 + 8 * g];
    }

    // =========== MC2 (A,B) ===========
    v8s awA0, awA1, awB0, awB1;
    {
        float b0 = p.mc_b2[c], b1 = p.mc_b2[16 + c], b2 = p.mc_b2[32 + c], b3 = p.mc_b2[48 + c];
        v4f x0A = {b0, b0, b0, b0}, x1A = {b1, b1, b1, b1}, x2A = {b2, b2, b2, b2}, x3A = {b3, b3, b3, b3};
        v4f x0B = x0A, x1B = x1A, x2B = x2A, x3B = x3A;
        {
            v8s W;
            W = wb[2560 + 0 * 64 + L]; x0A = MFMA16(amA0, W, x0A); x0B = MFMA16(amB0, W, x0B);
            W = wb[2560 + 4 * 64 + L]; x0A = MFMA16(amA1, W, x0A); x0B = MFMA16(amB1, W, x0B);
            W = wb[2560 + 1 * 64 + L]; x1A = MFMA16(amA0, W, x1A); x1B = MFMA16(amB0, W, x1B);
            W = wb[2560 + 5 * 64 + L]; x1A = MFMA16(amA1, W, x1A); x1B = MFMA16(amB1, W, x1B);
            W = wb[2560 + 2 * 64 + L]; x2A = MFMA16(amA0, W, x2A); x2B = MFMA16(amB0, W, x2B);
            W = wb[2560 + 6 * 64 + L]; x2A = MFMA16(amA1, W, x2A); x2B = MFMA16(amB1, W, x2B);
            W = wb[2560 + 3 * 64 + L]; x3A = MFMA16(amA0, W, x3A); x3B = MFMA16(amB0, W, x3B);
            W = wb[2560 + 7 * 64 + L]; x3A = MFMA16(amA1, W, x3A); x3B = MFMA16(amB1, W, x3B);
        }
        x0A *= tsvA; x1A *= tsvA; x2A *= tsvA; x3A *= tsvA;
        x0B *= tsvB; x1B *= tsvB; x2B *= tsvB; x3B *= tsvB;
        float lg0 = p.mn_ln_g[c], lg1 = p.mn_ln_g[16 + c], lg2 = p.mn_ln_g[32 + c], lg3 = p.mn_ln_g[48 + c];
        float lb0 = p.mn_ln_b[c], lb1 = p.mn_ln_b[16 + c], lb2 = p.mn_ln_b[32 + c], lb3 = p.mn_ln_b[48 + c];
        ln_c64<false>(x0A, x1A, x2A, x3A, lg0, lg1, lg2, lg3, lb0, lb1, lb2, lb3);
        ln_c64<false>(x0B, x1B, x2B, x3B, lg0, lg1, lg2, lg3, lb0, lb1, lb2, lb3);
        store_c(xp[w][0], 0, L, x0A, x1A, x2A, x3A);
        store_c(xp[w][1], 0, L, x0B, x1B, x2B, x3B);
        LDS_ORDER();
        awA0 = *(const v8s *)&xp[w][0][c][0 + 8 * g];
        awA1 = *(const v8s *)&xp[w][0][c][32 + 8 * g];
        awB0 = *(const v8s *)&xp[w][1][c][0 + 8 * g];
        awB1 = *(const v8s *)&xp[w][1][c][32 + 8 * g];
    }

    // =========== AT: Q,K stored per-tile; V kept in regs ===========
    v4f vtA0, vtA1, vtA2, vtA3, vtB0, vtB1, vtB2, vtB3;
    {
#define AT_QK(T, DSTC)                                                          \
        { float _b = p.at_in_b[16 * (T) + c];                                    \
          v8s W0 = wb[3072 + (T) * 64 + L], W1 = wb[3072 + (12 + (T)) * 64 + L]; \
          v4f aA = {_b, _b, _b, _b}, aB = aA;                                    \
          aA = MFMA16(awA0, W0, aA); aA = MFMA16(awA1, W1, aA);                  \
          aB = MFMA16(awB0, W0, aB); aB = MFMA16(awB1, W1, aB);                  \
          unsigned uA01 = cvtpk(aA[0], aA[1]), uA23 = cvtpk(aA[2], aA[3]);       \
          unsigned uB01 = cvtpk(aB[0], aB[1]), uB23 = cvtpk(aB[2], aB[3]);       \
          xp[w][0][4 * g + 0][(DSTC) + c] = (unsigned short)uA01;                \
          xp[w][0][4 * g + 1][(DSTC) + c] = (unsigned short)(uA01 >> 16);        \
          xp[w][0][4 * g + 2][(DSTC) + c] = (unsigned short)uA23;                \
          xp[w][0][4 * g + 3][(DSTC) + c] = (unsigned short)(uA23 >> 16);        \
          xp[w][1][4 * g + 0][(DSTC) + c] = (unsigned short)uB01;                \
          xp[w][1][4 * g + 1][(DSTC) + c] = (unsigned short)(uB01 >> 16);        \
          xp[w][1][4 * g + 2][(DSTC) + c] = (unsigned short)uB23;                \
          xp[w][1][4 * g + 3][(DSTC) + c] = (unsigned short)(uB23 >> 16); }
        AT_QK(0, 0)  AT_QK(1, 16)  AT_QK(2, 32)  AT_QK(3, 48)
        AT_QK(4, 64) AT_QK(5, 80)  AT_QK(6, 96)  AT_QK(7, 112)
#undef AT_QK
#define AT_V(T, VA, VB)                                                          \
        { float _b = p.at_in_b[16 * (T) + c];                                    \
          v8s W0 = wb[3072 + (T) * 64 + L], W1 = wb[3072 + (12 + (T)) * 64 + L]; \
          VA = (v4f){_b, _b, _b, _b}; VB = VA;                                   \
          VA = MFMA16(awA0, W0, VA); VA = MFMA16(awA1, W1, VA);                  \
          VB = MFMA16(awB0, W0, VB); VB = MFMA16(awB1, W1, VB); }
        AT_V(8, vtA0, vtB0) AT_V(9, vtA1, vtB1) AT_V(10, vtA2, vtB2) AT_V(11, vtA3, vtB3)
#undef AT_V
        LDS_ORDER();
    }

    // =========== attention (A,B) ===========
    float agA0, agA1, agA2, agA3, agB0, agB1, agB2, agB3;
#define ATTN(TI, VT0, VT1, VT2, VT3, O0, O1, O2, O3)                              \
    {                                                                             \
        const v4f z4 = {0.f, 0.f, 0.f, 0.f};                                      \
        v4f s0, s1, s2, s3;                                                       \
        {                                                                         \
            v8s aq, bk;                                                           \
            aq = (g < 2) ? *(const v8s *)&xp[w][TI][c][0 + 8 * g] : zf;           \
            bk = (g < 2) ? *(const v8s *)&xp[w][TI][c][64 + 0 + 8 * g] : zf;      \
            s0 = MFMA16(aq, bk, z4);                                              \
            aq = (g < 2) ? *(const v8s *)&xp[w][TI][c][16 + 8 * g] : zf;          \
            bk = (g < 2) ? *(const v8s *)&xp[w][TI][c][64 + 16 + 8 * g] : zf;     \
            s1 = MFMA16(aq, bk, z4);                                              \
            aq = (g < 2) ? *(const v8s *)&xp[w][TI][c][32 + 8 * g] : zf;          \
            bk = (g < 2) ? *(const v8s *)&xp[w][TI][c][64 + 32 + 8 * g] : zf;     \
            s2 = MFMA16(aq, bk, z4);                                              \
            aq = (g < 2) ? *(const v8s *)&xp[w][TI][c][48 + 8 * g] : zf;          \
            bk = (g < 2) ? *(const v8s *)&xp[w][TI][c][64 + 48 + 8 * g] : zf;     \
            s3 = MFMA16(aq, bk, z4);                                              \
        }                                                                         \
        if (c >= N_) {                                                            \
            v4f neg = {-1e30f, -1e30f, -1e30f, -1e30f};                           \
            s0 = neg; s1 = neg; s2 = neg; s3 = neg;                               \
        }                                                                         \
        v4f m0 = s0, m1 = s1, m2 = s2, m3 = s3;                                   \
        _Pragma("unroll")                                                         \
        for (int o = 1; o < 16; o <<= 1)                                          \
            _Pragma("unroll")                                                     \
            for (int r = 0; r < 4; r++) {                                         \
                m0[r] = fmaxf(m0[r], __shfl_xor(m0[r], o, 64));                   \
                m1[r] = fmaxf(m1[r], __shfl_xor(m1[r], o, 64));                   \
                m2[r] = fmaxf(m2[r], __shfl_xor(m2[r], o, 64));                   \
                m3[r] = fmaxf(m3[r], __shfl_xor(m3[r], o, 64));                   \
            }                                                                     \
        v4f e0, e1, e2, e3;                                                       \
        _Pragma("unroll")                                                         \
        for (int r = 0; r < 4; r++) {                                             \
            e0[r] = __expf((s0[r] - m0[r]) * 0.25f);                              \
            e1[r] = __expf((s1[r] - m1[r]) * 0.25f);                              \
            e2[r] = __expf((s2[r] - m2[r]) * 0.25f);                              \
            e3[r] = __expf((s3[r] - m3[r]) * 0.25f);                              \
        }                                                                         \
        v4f z0 = e0, z1 = e1, z2 = e2, z3 = e3;                                   \
        _Pragma("unroll")                                                         \
        for (int o = 1; o < 16; o <<= 1)                                          \
            _Pragma("unroll")                                                     \
            for (int r = 0; r < 4; r++) {                                         \
                z0[r] += __shfl_xor(z0[r], o, 64);                                \
                z1[r] += __shfl_xor(z1[r], o, 64);                                \
                z2[r] += __shfl_xor(z2[r], o, 64);                                \
                z3[r] += __shfl_xor(z3[r], o, 64);                                \
            }                                                                     \
        _Pragma("unroll")                                                         \
        for (int r = 0; r < 4; r++) {                                             \
            e0[r] *= __builtin_amdgcn_rcpf(z0[r]);                                \
            e1[r] *= __builtin_amdgcn_rcpf(z1[r]);                                \
            e2[r] *= __builtin_amdgcn_rcpf(z2[r]);                                \
            e3[r] *= __builtin_amdgcn_rcpf(z3[r]);                                \
        }                                                                         \
        int row0 = 4 * g;                                                         \
        float cs0 = e0[0], cs1 = e1[0], cs2 = e2[0], cs3 = e3[0];                 \
        _Pragma("unroll")                                                         \
        for (int r = 1; r < 4; r++) {                                             \
            bool ok = (row0 + r) < N_;                                            \
            cs0 += ok ? e0[r] : 0.f; cs1 += ok ? e1[r] : 0.f;                     \
            cs2 += ok ? e2[r] : 0.f; cs3 += ok ? e3[r] : 0.f;                     \
        }                                                                         \
        cs0 += __shfl_xor(cs0, 16, 64); cs0 += __shfl_xor(cs0, 32, 64);           \
        cs1 += __shfl_xor(cs1, 16, 64); cs1 += __shfl_xor(cs1, 32, 64);           \
        cs2 += __shfl_xor(cs2, 16, 64); cs2 += __shfl_xor(cs2, 32, 64);           \
        cs3 += __shfl_xor(cs3, 16, 64); cs3 += __shfl_xor(cs3, 32, 64);           \
        int pbase = (((L & 48) + ((L & 48) >> 2)) << 2);                          \
        O0 = 0.f; O1 = 0.f; O2 = 0.f; O3 = 0.f;                                   \
        _Pragma("unroll")                                                         \
        for (int r = 0; r < 4; r++) {                                             \
            int pa = pbase + 4 * r;                                               \
            float c0 = __int_as_float(__builtin_amdgcn_ds_bpermute(pa, __float_as_int(cs0))); \
            float c1 = __int_as_float(__builtin_amdgcn_ds_bpermute(pa, __float_as_int(cs1))); \
            float c2 = __int_as_float(__builtin_amdgcn_ds_bpermute(pa, __float_as_int(cs2))); \
            float c3 = __int_as_float(__builtin_amdgcn_ds_bpermute(pa, __float_as_int(cs3))); \
            O0 += c0 * VT0[r]; O1 += c1 * VT1[r];                                 \
            O2 += c2 * VT2[r]; O3 += c3 * VT3[r];                                 \
        }                                                                         \
        O0 += __shfl_xor(O0, 16, 64); O0 += __shfl_xor(O0, 32, 64);               \
        O1 += __shfl_xor(O1, 16, 64); O1 += __shfl_xor(O1, 32, 64);               \
        O2 += __shfl_xor(O2, 16, 64); O2 += __shfl_xor(O2, 32, 64);               \
        O3 += __shfl_xor(O3, 16, 64); O3 += __shfl_xor(O3, 32, 64);               \
        const float inv13 = 1.0f / 13.0f;                                         \
        O0 *= inv13; O1 *= inv13; O2 *= inv13; O3 *= inv13;                       \
    }
    ATTN(0, vtA0, vtA1, vtA2, vtA3, agA0, agA1, agA2, agA3)
    ATTN(1, vtB0, vtB1, vtB2, vtB3, agB0, agB1, agB2, agB3)
#undef ATTN

    // ============================================================
    // block-cooperative node phase: 8 tasks = MFMA rows 0..7; output rows
    // 8..15 discarded (writes skipped with g<2 -- stale A-rows only feed
    // discarded C-rows).  bf16 hi/lo split, 3-term MFMA product.
    // ============================================================
    const int rA = 2 * w, rB = rA + 1;

    __syncthreads();                 // all waves done with xp (attention)
    if (g == 0) {                    // stage ag -> buf0 rows rA,rB cols 0..63
        wr_hl2(XNP(0, 0, rA, c),      XNP(0, 1, rA, c),      agA0,
               XNP(0, 0, rA, 16 + c), XNP(0, 1, rA, 16 + c), agA1);
        wr_hl2(XNP(0, 0, rA, 32 + c), XNP(0, 1, rA, 32 + c), agA2,
               XNP(0, 0, rA, 48 + c), XNP(0, 1, rA, 48 + c), agA3);
        wr_hl2(XNP(0, 0, rB, c),      XNP(0, 1, rB, c),      agB0,
               XNP(0, 0, rB, 16 + c), XNP(0, 1, rB, 16 + c), agB1);
        wr_hl2(XNP(0, 0, rB, 32 + c), XNP(0, 1, rB, 32 + c), agB2,
               XNP(0, 0, rB, 48 + c), XNP(0, 1, rB, 48 + c), agB3);
    }
    __syncthreads();

    // ---- N1: at_out  [8x64] @ [64x64]; wave w owns ntile w; buf0 -> buf1
    {
        const v8s *WH = (const v8s *)(NW + NW_AOH);
        const v8s *WL = (const v8s *)(NW + NW_AOL);
        float bb = p.at_out_b[16 * w + c];
        v4f acc = {bb, bb, bb, bb};
#pragma unroll
        for (int kc = 0; kc < 2; kc++) {
            v8s xh = *(const v8s *)XNP(0, 0, c, 8 * g + 32 * kc);
            v8s xl = *(const v8s *)XNP(0, 1, c, 8 * g + 32 * kc);
            v8s wh = WH[(kc * 4 + w) * 64 + L];
            v8s wl = WL[(kc * 4 + w) * 64 + L];
            acc = MFMA16(xh, wl, acc);
            acc = MFMA16(xl, wh, acc);
            acc = MFMA16(xh, wh, acc);
        }
        if (g < 2) {
            wr_hl2(XNP(1, 0, 4 * g + 0, 16 * w + c), XNP(1, 1, 4 * g + 0, 16 * w + c), acc[0],
                   XNP(1, 0, 4 * g + 1, 16 * w + c), XNP(1, 1, 4 * g + 1, 16 * w + c), acc[1]);
            wr_hl2(XNP(1, 0, 4 * g + 2, 16 * w + c), XNP(1, 1, 4 * g + 2, 16 * w + c), acc[2],
                   XNP(1, 0, 4 * g + 3, 16 * w + c), XNP(1, 1, 4 * g + 3, 16 * w + c), acc[3]);
        }
    }
    __syncthreads();

    // ---- N2: ag1  [8x64] @ [64x128]; wave w owns ntiles 2w,2w+1; buf1 -> buf0
    {
        const v8s *WH = (const v8s *)(NW + NW_AG1H);
        const v8s *WL = (const v8s *)(NW + NW_AG1L);
        const int nt0 = 2 * w, nt1 = nt0 + 1;
        float b0 = p.ag_b1[16 * nt0 + c], b1 = p.ag_b1[16 * nt1 + c];
        v4f a0 = {b0, b0, b0, b0}, a1 = {b1, b1, b1, b1};
#pragma unroll
        for (int kc = 0; kc < 2; kc++) {
            v8s xh = *(const v8s *)XNP(1, 0, c, 8 * g + 32 * kc);
            v8s xl = *(const v8s *)XNP(1, 1, c, 8 * g + 32 * kc);
            v8s wh0 = WH[(kc * 8 + nt0) * 64 + L], wl0 = WL[(kc * 8 + nt0) * 64 + L];
            v8s wh1 = WH[(kc * 8 + nt1) * 64 + L], wl1 = WL[(kc * 8 + nt1) * 64 + L];
            a0 = MFMA16(xh, wl0, a0); a1 = MFMA16(xh, wl1, a1);
            a0 = MFMA16(xl, wh0, a0); a1 = MFMA16(xl, wh1, a1);
            a0 = MFMA16(xh, wh0, a0); a1 = MFMA16(xh, wh1, a1);
        }
        if (g < 2) {
#pragma unroll
            for (int r = 0; r < 4; r += 2) {
                wr_hl2(XNP(0, 0, 4 * g + r,     16 * nt0 + c), XNP(0, 1, 4 * g + r,     16 * nt0 + c), a0[r],
                       XNP(0, 0, 4 * g + r + 1, 16 * nt0 + c), XNP(0, 1, 4 * g + r + 1, 16 * nt0 + c), a0[r + 1]);
                wr_hl2(XNP(0, 0, 4 * g + r,     16 * nt1 + c), XNP(0, 1, 4 * g + r,     16 * nt1 + c), a1[r],
                       XNP(0, 0, 4 * g + r + 1, 16 * nt1 + c), XNP(0, 1, 4 * g + r + 1, 16 * nt1 + c), a1[r + 1]);
            }
        }
    }
    __syncthreads();

    // ---- LN+gelu pass: each wave LNs its own 2 tasks; buf0 -> buf1
    {
        float xA0 = bs2f(*XNP(0, 0, rA, L))      + bs2f(*XNP(0, 1, rA, L));
        float xA1 = bs2f(*XNP(0, 0, rA, 64 + L)) + bs2f(*XNP(0, 1, rA, 64 + L));
        float xB0 = bs2f(*XNP(0, 0, rB, L))      + bs2f(*XNP(0, 1, rB, L));
        float xB1 = bs2f(*XNP(0, 0, rB, 64 + L)) + bs2f(*XNP(0, 1, rB, 64 + L));
        float lg0 = p.ag_ln_g[L], lg1 = p.ag_ln_g[L + 64];
        float lb0 = p.ag_ln_b[L], lb1 = p.ag_ln_b[L + 64];
        ln128<true>(xA0, xA1, lg0, lg1, lb0, lb1);
        ln128<true>(xB0, xB1, lg0, lg1, lb0, lb1);
        wr_hl2(XNP(1, 0, rA, L),      XNP(1, 1, rA, L),      xA0,
               XNP(1, 0, rA, 64 + L), XNP(1, 1, rA, 64 + L), xA1);
        wr_hl2(XNP(1, 0, rB, L),      XNP(1, 1, rB, L),      xB0,
               XNP(1, 0, rB, 64 + L), XNP(1, 1, rB, 64 + L), xB1);
    }
    __syncthreads();

    // ---- N3: ag2  [8x128] @ [128x128] -> ni; buf1 -> buf0 cols 128..255.
    //      also stage node_states (gate cols 0..127) and keep fp32 copies.
    const float *nstA = p.node_states + ((size_t)bsA * N_ + tA) * D_;
    const float *nstB = p.node_states + ((size_t)bsB * N_ + tB) * D_;
    float nA0 = nstA[L], nA1 = nstA[L + 64];
    float nB0 = nstB[L], nB1 = nstB[L + 64];
    {
        const v8s *WH = (const v8s *)(NW + NW_AG2H);
        const v8s *WL = (const v8s *)(NW + NW_AG2L);
        const int nt0 = 2 * w, nt1 = nt0 + 1;
        float b0 = p.ag_b2[16 * nt0 + c], b1 = p.ag_b2[16 * nt1 + c];
        v4f a0 = {b0, b0, b0, b0}, a1 = {b1, b1, b1, b1};
#pragma unroll
        for (int kc = 0; kc < 4; kc++) {
            v8s xh = *(const v8s *)XNP(1, 0, c, 8 * g + 32 * kc);
            v8s xl = *(const v8s *)XNP(1, 1, c, 8 * g + 32 * kc);
            v8s wh0 = WH[(kc * 8 + nt0) * 64 + L], wl0 = WL[(kc * 8 + nt0) * 64 + L];
            v8s wh1 = WH[(kc * 8 + nt1) * 64 + L], wl1 = WL[(kc * 8 + nt1) * 64 + L];
            a0 = MFMA16(xh, wl0, a0); a1 = MFMA16(xh, wl1, a1);
            a0 = MFMA16(xl, wh0, a0); a1 = MFMA16(xl, wh1, a1);
            a0 = MFMA16(xh, wh0, a0); a1 = MFMA16(xh, wh1, a1);
        }
        if (g < 2) {
#pragma unroll
            for (int r = 0; r < 4; r += 2) {
                wr_hl2(XNP(0, 0, 4 * g + r,     128 + 16 * nt0 + c), XNP(0, 1, 4 * g + r,     128 + 16 * nt0 + c), a0[r],
                       XNP(0, 0, 4 * g + r + 1, 128 + 16 * nt0 + c), XNP(0, 1, 4 * g + r + 1, 128 + 16 * nt0 + c), a0[r + 1]);
                wr_hl2(XNP(0, 0, 4 * g + r,     128 + 16 * nt1 + c), XNP(0, 1, 4 * g + r,     128 + 16 * nt1 + c), a1[r],
                       XNP(0, 0, 4 * g + r + 1, 128 + 16 * nt1 + c), XNP(0, 1, 4 * g + r + 1, 128 + 16 * nt1 + c), a1[r + 1]);
            }
        }
        wr_hl2(XNP(0, 0, rA, L),      XNP(0, 1, rA, L),      nA0,
               XNP(0, 0, rA, 64 + L), XNP(0, 1, rA, 64 + L), nA1);
        wr_hl2(XNP(0, 0, rB, L),      XNP(0, 1, rB, L),      nB0,
               XNP(0, 0, rB, 64 + L), XNP(0, 1, rB, 64 + L), nB1);
    }
    __syncthreads();

    // ---- N4: gate  [8x256] @ [256x128]; buf0 -> buf1 (gpre)
    {
        const v8s *WH = (const v8s *)(NW + NW_GTH);
        const v8s *WL = (const v8s *)(NW + NW_GTL);
        const int nt0 = 2 * w, nt1 = nt0 + 1;
        float b0 = p.gt_b[16 * nt0 + c], b1 = p.gt_b[16 * nt1 + c];
        v4f a0 = {b0, b0, b0, b0}, a1 = {b1, b1, b1, b1};
#pragma unroll
        for (int kc = 0; kc < 8; kc++) {
            v8s xh = *(const v8s *)XNP(0, 0, c, 8 * g + 32 * kc);
            v8s xl = *(const v8s *)XNP(0, 1, c, 8 * g + 32 * kc);
            v8s wh0 = WH[(kc * 8 + nt0) * 64 + L], wl0 = WL[(kc * 8 + nt0) * 64 + L];
            v8s wh1 = WH[(kc * 8 + nt1) * 64 + L], wl1 = WL[(kc * 8 + nt1) * 64 + L];
            a0 = MFMA16(xh, wl0, a0); a1 = MFMA16(xh, wl1, a1);
            a0 = MFMA16(xl, wh0, a0); a1 = MFMA16(xl, wh1, a1);
            a0 = MFMA16(xh, wh0, a0); a1 = MFMA16(xh, wh1, a1);
        }
        if (g < 2) {
#pragma unroll
            for (int r = 0; r < 4; r += 2) {
                wr_hl2(XNP(1, 0, 4 * g + r,     16 * nt0 + c), XNP(1, 1, 4 * g + r,     16 * nt0 + c), a0[r],
                       XNP(1, 0, 4 * g + r + 1, 16 * nt0 + c), XNP(1, 1, 4 * g + r + 1, 16 * nt0 + c), a0[r + 1]);
                wr_hl2(XNP(1, 0, 4 * g + r,     16 * nt1 + c), XNP(1, 1, 4 * g + r,     16 * nt1 + c), a1[r],
                       XNP(1, 0, 4 * g + r + 1, 16 * nt1 + c), XNP(1, 1, 4 * g + r + 1, 16 * nt1 + c), a1[r + 1]);
            }
        }
    }
    __syncthreads();

    // ---- final: sigmoid gate, update, node LN, store
    {
        float gpA0 = bs2f(*XNP(1, 0, rA, L))      + bs2f(*XNP(1, 1, rA, L));
        float gpA1 = bs2f(*XNP(1, 0, rA, 64 + L)) + bs2f(*XNP(1, 1, rA, 64 + L));
        float gpB0 = bs2f(*XNP(1, 0, rB, L))      + bs2f(*XNP(1, 1, rB, L));
        float gpB1 = bs2f(*XNP(1, 0, rB, 64 + L)) + bs2f(*XNP(1, 1, rB, 64 + L));
        float niA0 = bs2f(*XNP(0, 0, rA, 128 + L)) + bs2f(*XNP(0, 1, rA, 128 + L));
        float niA1 = bs2f(*XNP(0, 0, rA, 192 + L)) + bs2f(*XNP(0, 1, rA, 192 + L));
        float niB0 = bs2f(*XNP(0, 0, rB, 128 + L)) + bs2f(*XNP(0, 1, rB, 128 + L));
        float niB1 = bs2f(*XNP(0, 0, rB, 192 + L)) + bs2f(*XNP(0, 1, rB, 192 + L));
        float gA0 = sigm(gpA0), gA1 = sigm(gpA1);
        float gB0 = sigm(gpB0), gB1 = sigm(gpB1);
        float updA0 = gA0 * niA0 + (1.f - gA0) * nA0;
        float updA1 = gA1 * niA1 + (1.f - gA1) * nA1;
        float updB0 = gB0 * niB0 + (1.f - gB0) * nB0;
        float updB1 = gB1 * niB1 + (1.f - gB1) * nB1;
        float lg0 = p.nn_ln_g[L], lg1 = p.nn_ln_g[L + 64];
        float lb0 = p.nn_ln_b[L], lb1 = p.nn_ln_b[L + 64];
        ln128<false>(updA0, updA1, lg0, lg1, lb0, lb1);
        ln128<false>(updB0, updB1, lg0, lg1, lb0, lb1);
        float *opA = p.out + ((size_t)bsA * N_ + tA) * D_;
        float *opB = p.out + ((size_t)bsB * N_ + tB) * D_;
        opA[L] = updA0; opA[L + 64] = updA1;
        opB[L] = updB0; opB[L + 64] = updB1;
    }
#undef XNP
}

extern "C" void kernel_launch(void* const* d_in, const int* in_sizes, int n_in,
                              void* d_out, int out_size, void* d_ws, size_t ws_size,
                              hipStream_t stream) {
    Params p;
    p.node_states   = (const float*)d_in[0];
    p.edge_features = (const float*)d_in[1];
    p.ee_w1   = (const float*)d_in[2];
    p.ee_b1   = (const float*)d_in[3];
    p.ee_ln_g = (const float*)d_in[4];
    p.ee_ln_b = (const float*)d_in[5];
    p.ee_w2   = (const float*)d_in[6];
    p.ee_b2   = (const float*)d_in[7];
    p.ts_w1   = (const float*)d_in[8];
    p.ts_b1   = (const float*)d_in[9];
    p.ts_ln_g = (const float*)d_in[10];
    p.ts_ln_b = (const float*)d_in[11];
    p.ts_w2   = (const float*)d_in[12];
    p.ts_b2   = (const float*)d_in[13];
    p.ts_w3   = (const float*)d_in[14];
    p.ts_b3   = (const float*)d_in[15];
    p.mc_w1   = (const float*)d_in[16];
    p.mc_b1   = (const float*)d_in[17];
    p.mc_ln_g = (const float*)d_in[18];
    p.mc_ln_b = (const float*)d_in[19];
    p.mc_w2   = (const float*)d_in[20];
    p.mc_b2   = (const float*)d_in[21];
    p.at_in_w  = (const float*)d_in[22];
    p.at_in_b  = (const float*)d_in[23];
    p.at_out_w = (const float*)d_in[24];
    p.at_out_b = (const float*)d_in[25];
    p.ag_w1   = (const float*)d_in[26];
    p.ag_b1   = (const float*)d_in[27];
    p.ag_ln_g = (const float*)d_in[28];
    p.ag_ln_b = (const float*)d_in[29];
    p.ag_w2   = (const float*)d_in[30];
    p.ag_b2   = (const float*)d_in[31];
    p.gt_w    = (const float*)d_in[32];
    p.gt_b    = (const float*)d_in[33];
    p.nn_ln_g = (const float*)d_in[34];
    p.nn_ln_b = (const float*)d_in[35];
    p.mn_ln_g = (const float*)d_in[36];
    p.mn_ln_b = (const float*)d_in[37];
    p.ws      = (float*)d_ws;
    p.out     = (float*)d_out;

    const int prep_threads = F_TOTAL + H_TOTAL;
    hipLaunchKernelGGL(prep_kernel, dim3((prep_threads + 255) / 256), dim3(256), 0, stream, p);
    hipLaunchKernelGGL(petri_kernel, dim3((B_ * S_ * N_) / 8), dim3(256), 0, stream, p);
}